// Round 10
// baseline (74.209 us; speedup 1.0000x reference)
//
#include <hip/hip_runtime.h>
#include <math.h>

typedef unsigned short u16;
typedef unsigned int u32;
typedef __attribute__((ext_vector_type(8))) short bf16x8;
typedef __attribute__((ext_vector_type(4))) float f32x4;
typedef __attribute__((ext_vector_type(4))) u32 u32x4;

// ---------------- bf16 helpers (manual RNE; inputs are finite) ----------------
__device__ __forceinline__ u16 f2bf(float x) {
    u32 b = __builtin_bit_cast(u32, x);
    b += 0x7FFFu + ((b >> 16) & 1u);
    return (u16)(b >> 16);
}
__device__ __forceinline__ float bf2f(u16 u) {
    u32 b = ((u32)u) << 16;
    return __builtin_bit_cast(float, b);
}

// Swizzled tiled plane address, in 16-byte units.
__device__ __forceinline__ size_t sw_unit(int row, int c, int CC) {
    int slot = (c & 63) >> 3;
    return ((size_t)((row >> 7) * CC + (c >> 6)) << 10)
         + (size_t)((row & 127) << 3) + (size_t)(slot ^ (row & 7));
}

// ---------------------------------------------------------------------------
// prep (R5-proven): activations -> swizzled hi/lo planes; weights -> hi(+lo).
// ---------------------------------------------------------------------------
__device__ void prep_x(const float* __restrict__ X, int C, int HW, int bl, int PT,
                       u16* __restrict__ dh, u16* __restrict__ dl) {
    __shared__ float Xt[64][65];
    const int t = threadIdx.x;
    const int pt = bl % PT, ct = bl / PT;
    const int p0 = pt * 64, c0 = ct * 64;
    const int b = p0 / HW, hw0 = p0 % HW;
    #pragma unroll
    for (int i = 0; i < 16; i++) {
        int r = (t >> 6) + i * 4;
        Xt[r][t & 63] = X[(size_t)(b * C + c0 + r) * HW + hw0 + (t & 63)];
    }
    __syncthreads();
    const int CC = C >> 6;
    #pragma unroll
    for (int it = 0; it < 2; it++) {
        int id = t + it * 256;
        int px = id >> 3, sl = id & 7;
        bf16x8 hv, lv;
        #pragma unroll
        for (int j = 0; j < 8; j++) {
            float x = Xt[sl * 8 + j][px];
            u16 h = f2bf(x);
            hv[j] = (short)h;
            lv[j] = (short)f2bf(x - bf2f(h));
        }
        size_t unit = sw_unit(p0 + px, c0 + sl * 8, CC);
        *(bf16x8*)(dh + unit * 8) = hv;
        *(bf16x8*)(dl + unit * 8) = lv;
    }
}

__device__ void prep_w(const float* __restrict__ W, int C, int bl,
                       u16* __restrict__ dh, u16* __restrict__ dl, bool wlo) {
    const int t = threadIdx.x;
    const int ot = bl & 3, cc = bl >> 2;
    const int o0 = ot * 64, c0 = cc * 64;
    const int CC = C >> 6;
    #pragma unroll
    for (int it = 0; it < 2; it++) {
        int id = t + it * 256;
        int ol = id >> 3, sl = id & 7;
        int o = o0 + ol, c = c0 + sl * 8;
        const float* wp = W + (size_t)o * C + c;
        float4 a = *(const float4*)wp;
        float4 b2 = *(const float4*)(wp + 4);
        float xs[8] = {a.x, a.y, a.z, a.w, b2.x, b2.y, b2.z, b2.w};
        bf16x8 hv, lv;
        #pragma unroll
        for (int j = 0; j < 8; j++) {
            u16 h = f2bf(xs[j]);
            hv[j] = (short)h;
            lv[j] = (short)f2bf(xs[j] - bf2f(h));
        }
        size_t unit = sw_unit(o, c, CC);
        *(bf16x8*)(dh + unit * 8) = hv;
        if (wlo) *(bf16x8*)(dl + unit * 8) = lv;
    }
}

// W plane offsets (u16 units) inside Whi/Wlo
#define OFF_WQ 0
#define OFF_WK0 65536
#define OFF_WV0 163840
#define OFF_WK1 262144
#define OFF_WV1 458752
#define OFF_WFUSE 655360

__global__ __launch_bounds__(256) void prep_k(
    const float* __restrict__ query, const float* __restrict__ mem0, const float* __restrict__ mem1,
    const float* __restrict__ Wq, const float* __restrict__ Wk0, const float* __restrict__ Wv0,
    const float* __restrict__ Wk1, const float* __restrict__ Wv1, const float* __restrict__ Wfuse,
    u16* Xq_hi, u16* Xq_lo, u16* Xm0_hi, u16* Xm0_lo, u16* Xm1_hi, u16* Xm1_lo,
    u16* Whi, u16* Wlo)
{
    const int bx = blockIdx.x;
    if (bx < 512)      prep_x(query, 256, 4096, bx,       128, Xq_hi, Xq_lo);
    else if (bx < 704) prep_x(mem0,  384, 1024, bx - 512,  32, Xm0_hi, Xm0_lo);
    else if (bx < 800) prep_x(mem1,  768,  256, bx - 704,   8, Xm1_hi, Xm1_lo);
    else {
        int r = bx - 800;
        if (r < 16)       prep_w(Wq,    256, r,       Whi + OFF_WQ,    Wlo, false);
        else if (r < 40)  prep_w(Wk0,   384, r - 16,  Whi + OFF_WK0,   Wlo, false);
        else if (r < 64)  prep_w(Wv0,   384, r - 40,  Whi + OFF_WV0,   Wlo, false);
        else if (r < 112) prep_w(Wk1,   768, r - 64,  Whi + OFF_WK1,   Wlo, false);
        else if (r < 160) prep_w(Wv1,   768, r - 112, Whi + OFF_WV1,   Wlo, false);
        else              prep_w(Wfuse, 512, r - 160, Whi + OFF_WFUSE, Wlo + OFF_WFUSE, true);
    }
}

// ---------------------------------------------------------------------------
// 2-term split MFMA GEMM core: D = Ahi·Bhi + Alo·Bhi (+bias).
// Block 128x128, 4 waves of 64x64, KC=64, 3 LDS planes (48 KB), pipelined.
// Epilogue MODE: 0 = u16 pixel-major [row][256]
//                1 = v0t2 transposed+padded [b][256ch][40][40] (origin 4,3)
//                2 = v1t2 transposed+deinterleaved [b][256ch][30][2][16] (origin 4, col 2+x/2)
//                3 = f32 channel-major out [2][256][4096]
// ---------------------------------------------------------------------------
template<int MODE>
__device__ __forceinline__ void gemm_core(
    const u16* __restrict__ Ahi, const u16* __restrict__ Alo,
    const u16* __restrict__ Bhi, const float* __restrict__ bias,
    void* __restrict__ Y, int CC, int am, int bn, u16* smem)
{
    const int t = threadIdx.x, lane = t & 63, w = t >> 6;
    const int wr = w >> 1, wc = w & 1;
    const int l15 = lane & 15;

    f32x4 acc[4][4];
    #pragma unroll
    for (int a = 0; a < 4; a++)
        #pragma unroll
        for (int b2 = 0; b2 < 4; b2++)
            acc[a][b2] = (f32x4){0.f, 0.f, 0.f, 0.f};

    bf16x8 stg[3][4];
    {
        const size_t aoff = ((size_t)(am * CC)) << 13;
        const size_t boff = ((size_t)(bn * CC)) << 13;
        #pragma unroll
        for (int it = 0; it < 4; it++) {
            const size_t o = (size_t)(t + it * 256) * 8;
            stg[0][it] = *(const bf16x8*)(Ahi + aoff + o);
            stg[1][it] = *(const bf16x8*)(Alo + aoff + o);
            stg[2][it] = *(const bf16x8*)(Bhi + boff + o);
        }
    }

    for (int ck = 0; ck < CC; ck++) {
        __syncthreads();
        #pragma unroll
        for (int p = 0; p < 3; p++)
            #pragma unroll
            for (int it = 0; it < 4; it++)
                *(bf16x8*)(smem + p * 8192 + (size_t)(t + it * 256) * 8) = stg[p][it];
        __syncthreads();

        {
            const int cn = (ck + 1 < CC) ? ck + 1 : ck;
            const size_t aoff = ((size_t)(am * CC + cn)) << 13;
            const size_t boff = ((size_t)(bn * CC + cn)) << 13;
            #pragma unroll
            for (int it = 0; it < 4; it++) {
                const size_t o = (size_t)(t + it * 256) * 8;
                stg[0][it] = *(const bf16x8*)(Ahi + aoff + o);
                stg[1][it] = *(const bf16x8*)(Alo + aoff + o);
                stg[2][it] = *(const bf16x8*)(Bhi + boff + o);
            }
        }

        #pragma unroll
        for (int kk = 0; kk < 2; kk++) {
            bf16x8 ah[4], al[4], bh[4];
            #pragma unroll
            for (int tr = 0; tr < 4; tr++) {
                int row = wr * 64 + tr * 16 + l15;
                int off = row * 64 + (((kk * 4 + (lane >> 4)) ^ (row & 7)) << 3);
                ah[tr] = *(const bf16x8*)(smem + off);
                al[tr] = *(const bf16x8*)(smem + 8192 + off);
            }
            #pragma unroll
            for (int tc = 0; tc < 4; tc++) {
                int row = wc * 64 + tc * 16 + l15;
                int off = row * 64 + (((kk * 4 + (lane >> 4)) ^ (row & 7)) << 3);
                bh[tc] = *(const bf16x8*)(smem + 16384 + off);
            }
            #pragma unroll
            for (int tr = 0; tr < 4; tr++)
                #pragma unroll
                for (int tc = 0; tc < 4; tc++) {
                    acc[tr][tc] = __builtin_amdgcn_mfma_f32_16x16x32_bf16(ah[tr], bh[tc], acc[tr][tc], 0, 0, 0);
                    acc[tr][tc] = __builtin_amdgcn_mfma_f32_16x16x32_bf16(al[tr], bh[tc], acc[tr][tc], 0, 0, 0);
                }
        }
    }

    // ---- epilogue: D row = (lane>>4)*4+i, col = l15 (m89-verified) ----
    if (MODE == 3) {
        float* Yf = (float*)Y;
        #pragma unroll
        for (int tr = 0; tr < 4; tr++) {
            #pragma unroll
            for (int i = 0; i < 4; i++) {
                int o = am * 128 + wr * 64 + tr * 16 + ((lane >> 4) << 2) + i;
                float bv = bias[o];
                #pragma unroll
                for (int tc = 0; tc < 4; tc++) {
                    int pcol = bn * 128 + wc * 64 + tc * 16 + l15;
                    Yf[(size_t)((pcol >> 12) * 256 + o) * 4096 + (pcol & 4095)] = acc[tr][tc][i] + bv;
                }
            }
        }
    } else {
        u16* Y16 = (u16*)Y;
        float bv[4];
        #pragma unroll
        for (int tc = 0; tc < 4; tc++)
            bv[tc] = bias[bn * 128 + wc * 64 + tc * 16 + l15];
        #pragma unroll
        for (int tr = 0; tr < 4; tr++) {
            #pragma unroll
            for (int i = 0; i < 4; i++) {
                const int rp = am * 128 + wr * 64 + tr * 16 + ((lane >> 4) << 2) + i;
                if (MODE == 0) {
                    u16* yr = Y16 + (size_t)rp * 256 + bn * 128 + wc * 64 + l15;
                    #pragma unroll
                    for (int tc = 0; tc < 4; tc++)
                        yr[tc * 16] = f2bf(acc[tr][tc][i] + bv[tc]);
                } else {
                    int b, y, x;
                    if (MODE == 1) { b = rp >> 10; y = (rp >> 5) & 31; x = rp & 31; }
                    else           { b = rp >> 8;  y = (rp >> 4) & 15; x = rp & 15; }
                    #pragma unroll
                    for (int tc = 0; tc < 4; tc++) {
                        const int ch = bn * 128 + wc * 64 + tc * 16 + l15;
                        size_t idx;
                        if (MODE == 1)
                            idx = ((size_t)(b * 256 + ch) * 40 + y + 4) * 40 + x + 3;
                        else
                            idx = (((size_t)(b * 256 + ch) * 30 + y + 4) * 2 + (x & 1)) * 16 + 2 + (x >> 1);
                        Y16[idx] = f2bf(acc[tr][tc][i] + bv[tc]);
                    }
                }
            }
        }
    }
}

// proj: q / k0 / v0 / k1 / v1 in one 208-block dispatch
__global__ __launch_bounds__(256) void projmm_k(
    const u16* __restrict__ Xq_hi, const u16* __restrict__ Xq_lo,
    const u16* __restrict__ Xm0_hi, const u16* __restrict__ Xm0_lo,
    const u16* __restrict__ Xm1_hi, const u16* __restrict__ Xm1_lo,
    const u16* __restrict__ Whi,
    const float* __restrict__ bq, const float* __restrict__ bk0, const float* __restrict__ bv0,
    const float* __restrict__ bk1, const float* __restrict__ bv1,
    u16* qT, u16* k0T, u16* v0t2, u16* k1T, u16* v1t2)
{
    __shared__ u16 smem[24576];   // 48 KB
    const int bx = blockIdx.x;
    if (bx < 128) {
        gemm_core<0>(Xq_hi, Xq_lo, Whi + OFF_WQ, bq, (void*)qT, 4, bx >> 1, bx & 1, smem);
    } else if (bx < 192) {
        const int r = bx - 128, am = r >> 2, bnn = r & 3;
        if (bnn < 2) gemm_core<0>(Xm0_hi, Xm0_lo, Whi + OFF_WK0, bk0, (void*)k0T, 6, am, bnn, smem);
        else         gemm_core<1>(Xm0_hi, Xm0_lo, Whi + OFF_WV0, bv0, (void*)v0t2, 6, am, bnn - 2, smem);
    } else {
        const int r = bx - 192, am = r >> 2, bnn = r & 3;
        if (bnn < 2) gemm_core<0>(Xm1_hi, Xm1_lo, Whi + OFF_WK1, bk1, (void*)k1T, 12, am, bnn, smem);
        else         gemm_core<2>(Xm1_hi, Xm1_lo, Whi + OFF_WV1, bv1, (void*)v1t2, 12, am, bnn - 2, smem);
    }
}

__global__ __launch_bounds__(256) void fusemm_k(
    const u16* __restrict__ Whi, const u16* __restrict__ Wlo,
    const u16* __restrict__ fhi, const float* __restrict__ bfuse, float* out)
{
    __shared__ u16 smem[24576];
    const int bx = blockIdx.x;
    gemm_core<3>(Whi + OFF_WFUSE, Wlo + OFF_WFUSE, fhi, bfuse, (void*)out,
                 8, bx & 1, bx >> 1, smem);
}

// ---------------------------------------------------------------------------
// MFMA attention. V read from transposed+padded planes — no clamping needed:
// masked candidates have P = exp(-1e30 - m) = 0 exactly, so halo garbage
// (zeroed by memset) contributes nothing. Scale0: vf = 4 aligned u32 loads.
// Scale1: x de-interleaved by parity -> 8 contiguous u16.
// ---------------------------------------------------------------------------
template<int SCALE>
__device__ __forceinline__ void attn_mfma(
    const u16* __restrict__ qT, const u16* __restrict__ kT,
    const u16* __restrict__ vT2, u16* __restrict__ fhi,
    int b, int n, int ty, int tx, int lane, u16* s_lds)
{
    constexpr int HM = SCALE ? 16 : 32;
    const int qy0 = ty * 4, qx0 = tx * 4;
    const int ay0 = SCALE ? (qy0 >> 2) : (qy0 >> 1);
    const int ax0 = SCALE ? (qx0 >> 2) : (qx0 >> 1);
    const int l15 = lane & 15, kg = lane >> 4;

    const int pA = (b * 64 + qy0 + (l15 >> 2)) * 64 + qx0 + (l15 & 3);
    const bf16x8 qf = *(const bf16x8*)(qT + (size_t)pA * 256 + n * 32 + kg * 8);

    f32x4 s[4];
    #pragma unroll
    for (int t = 0; t < 4; t++) {
        const int cand = t * 16 + l15;
        const int wy = cand >> 3, wx = cand & 7;
        const int my = SCALE ? (ay0 + (wy - 2) * 2) : (ay0 - 3 + wy);
        const int mx = SCALE ? (ax0 + (wx - 2) * 2) : (ax0 - 3 + wx);
        const int myc = min(max(my, 0), HM - 1), mxc = min(max(mx, 0), HM - 1);
        const bf16x8 kf = *(const bf16x8*)(kT + (size_t)((b * HM + myc) * HM + mxc) * 256 + n * 32 + kg * 8);
        s[t] = __builtin_amdgcn_mfma_f32_16x16x32_bf16(qf, kf, (f32x4){0.f, 0.f, 0.f, 0.f}, 0, 0, 0);
    }

    const float scl = 0.17677669529663687f;
    float sv[4][4];
    #pragma unroll
    for (int t = 0; t < 4; t++) {
        const int cand = t * 16 + l15;
        const int wy = cand >> 3, wx = cand & 7;
        const int my = SCALE ? (ay0 + (wy - 2) * 2) : (ay0 - 3 + wy);
        const int mx = SCALE ? (ax0 + (wx - 2) * 2) : (ax0 - 3 + wx);
        const bool inb = (my >= 0) && (my < HM) && (mx >= 0) && (mx < HM);
        #pragma unroll
        for (int i = 0; i < 4; i++) {
            bool ok;
            if (SCALE) {
                ok = inb && (wy < 5) && (wx < 5);
            } else {
                const int r = kg * 4 + i;
                const int dy2 = (r >> 2) >> 1, dx2 = (r & 3) >> 1;
                ok = inb && ((u32)(wy - dy2) <= 6u) && ((u32)(wx - dx2) <= 6u);
            }
            sv[t][i] = ok ? s[t][i] * scl : -1e30f;
        }
    }

    float linv[4];
    #pragma unroll
    for (int i = 0; i < 4; i++) {
        float m = fmaxf(fmaxf(sv[0][i], sv[1][i]), fmaxf(sv[2][i], sv[3][i]));
        #pragma unroll
        for (int dd = 1; dd < 16; dd <<= 1) m = fmaxf(m, __shfl_xor(m, dd, 64));
        float l = 0.f;
        #pragma unroll
        for (int t = 0; t < 4; t++) { sv[t][i] = __expf(sv[t][i] - m); l += sv[t][i]; }
        #pragma unroll
        for (int dd = 1; dd < 16; dd <<= 1) l += __shfl_xor(l, dd, 64);
        linv[i] = 1.f / l;
    }

    #pragma unroll
    for (int t = 0; t < 4; t++)
        #pragma unroll
        for (int i = 0; i < 4; i++)
            s_lds[(kg * 4 + i) * 68 + t * 16 + l15] = f2bf(sv[t][i]);
    __syncthreads();

    f32x4 o[2] = {(f32x4){0.f,0.f,0.f,0.f}, (f32x4){0.f,0.f,0.f,0.f}};
    #pragma unroll
    for (int h = 0; h < 2; h++) {
        const bf16x8 pa = *(const bf16x8*)(s_lds + l15 * 68 + h * 32 + kg * 8);
        #pragma unroll
        for (int c = 0; c < 2; c++) {
            const int d = n * 32 + c * 16 + l15;
            bf16x8 vf;
            if (SCALE == 0) {
                const int ry = ay0 + 1 + h * 4 + kg;          // my+4, my = ay0-3+wy
                const u32* vp = (const u32*)(vT2 + ((size_t)(b * 256 + d) * 40 + ry) * 40 + ax0);
                u32x4 vv = {vp[0], vp[1], vp[2], vp[3]};
                vf = __builtin_bit_cast(bf16x8, vv);
            } else {
                const int ry = ay0 + 2 * (h * 4 + kg);        // my+4, my = ay0+(wy-2)*2
                const u16* vp = vT2 + (((size_t)(b * 256 + d) * 30 + ry) * 2 + (ax0 & 1)) * 16 + (ax0 >> 1);
                #pragma unroll
                for (int j = 0; j < 8; j++) vf[j] = (short)vp[j];
            }
            o[c] = __builtin_amdgcn_mfma_f32_16x16x32_bf16(pa, vf, o[c], 0, 0, 0);
        }
    }

    #pragma unroll
    for (int c = 0; c < 2; c++) {
        #pragma unroll
        for (int i = 0; i < 4; i++) {
            const int r = kg * 4 + i;
            const int p = (b * 64 + qy0 + (r >> 2)) * 64 + qx0 + (r & 3);
            const int ch = (SCALE ? 256 : 0) + n * 32 + c * 16 + l15;
            fhi[sw_unit(p, ch, 8) * 8 + (ch & 7)] = f2bf(o[c][i] * linv[i]);
        }
    }
}

__global__ __launch_bounds__(256) void attn_k(
    const u16* __restrict__ qT,
    const u16* __restrict__ k0T, const u16* __restrict__ v0t2,
    const u16* __restrict__ k1T, const u16* __restrict__ v1t2,
    u16* __restrict__ fhi)
{
    __shared__ u16 s_lds[4][16 * 68];
    const int t = threadIdx.x, w = t >> 6, lane = t & 63;
    const int bx = blockIdx.x;
    const int sc = bx >> 10;
    const int tile = (bx & 1023) * 4 + w;
    const int b = tile >> 11, n = (tile >> 8) & 7;
    const int ty = (tile >> 4) & 15, tx = tile & 15;
    if (sc == 0) attn_mfma<0>(qT, k0T, v0t2, fhi, b, n, ty, tx, lane, s_lds[w]);
    else         attn_mfma<1>(qT, k1T, v1t2, fhi, b, n, ty, tx, lane, s_lds[w]);
}

// ---------------------------------------------------------------------------
extern "C" void kernel_launch(void* const* d_in, const int* in_sizes, int n_in,
                              void* d_out, int out_size, void* d_ws, size_t ws_size,
                              hipStream_t stream)
{
    const float* query = (const float*)d_in[0];
    const float* mem0  = (const float*)d_in[1];
    const float* mem1  = (const float*)d_in[2];
    const float* Wq    = (const float*)d_in[3];  const float* bq    = (const float*)d_in[4];
    const float* Wk0   = (const float*)d_in[5];  const float* bk0   = (const float*)d_in[6];
    const float* Wv0   = (const float*)d_in[7];  const float* bv0   = (const float*)d_in[8];
    const float* Wk1   = (const float*)d_in[9];  const float* bk1   = (const float*)d_in[10];
    const float* Wv1   = (const float*)d_in[11]; const float* bv1   = (const float*)d_in[12];
    const float* Wfuse = (const float*)d_in[13]; const float* bfuse = (const float*)d_in[14];
    float* out = (float*)d_out;

    // workspace layout (bytes)
    char* ws = (char*)d_ws;
    u16* qT     = (u16*)(ws + 0);          // 4,194,304  (8192 x 256 bf16)
    u16* k0T    = (u16*)(ws + 4194304);    // 1,048,576  (2048 x 256)
    u16* k1T    = (u16*)(ws + 5242880);    //   262,144  (512 x 256)
    u16* v0t2   = (u16*)(ws + 5505024);    // 1,638,400  ([2][256][40][40])
    u16* v1t2   = (u16*)(ws + 7143424);    //   983,040  ([2][256][30][2][16])
    u16* Whi    = (u16*)(ws + 8388608);    // 1,572,864
    u16* Wlo    = (u16*)(ws + 9961472);    // 1,572,864
    u16* Xm0_hi = (u16*)(ws + 11534336);   // 1,572,864
    u16* Xm0_lo = (u16*)(ws + 13107200);   // 1,572,864
    u16* Xm1_hi = (u16*)(ws + 14680064);   //   786,432
    u16* Xm1_lo = (u16*)(ws + 15466496);   //   786,432
    u16* Xq_hi  = (u16*)(ws + 16252928);   // 4,194,304
    u16* Xq_lo  = (u16*)(ws + 20447232);   // 4,194,304
    u16* fhi    = Xq_hi;                   // fused plane (8 MB) aliases Xq planes

    // zero v-plane halos (P=0 masks them, but they must be finite)
    hipMemsetAsync(v0t2, 0, 1638400 + 983040, stream);

    prep_k<<<dim3(992), 256, 0, stream>>>(
        query, mem0, mem1, Wq, Wk0, Wv0, Wk1, Wv1, Wfuse,
        Xq_hi, Xq_lo, Xm0_hi, Xm0_lo, Xm1_hi, Xm1_lo, Whi, Wlo);

    projmm_k<<<dim3(208), 256, 0, stream>>>(
        Xq_hi, Xq_lo, Xm0_hi, Xm0_lo, Xm1_hi, Xm1_lo, Whi,
        bq, bk0, bv0, bk1, bv1, qT, k0T, v0t2, k1T, v1t2);

    attn_k<<<dim3(2048), 256, 0, stream>>>(qT, k0T, v0t2, k1T, v1t2, fhi);

    fusemm_k<<<dim3(128), 256, 0, stream>>>(Whi, Wlo, fhi, bfuse, out);
}

// Round 11
// 63.729 us; speedup vs baseline: 1.1644x; 1.1644x over previous
//
#include <hip/hip_runtime.h>
#include <math.h>

typedef unsigned short u16;
typedef unsigned int u32;
typedef __attribute__((ext_vector_type(8))) short bf16x8;
typedef __attribute__((ext_vector_type(4))) float f32x4;

// ---------------- bf16 helpers (manual RNE; inputs are finite) ----------------
__device__ __forceinline__ u16 f2bf(float x) {
    u32 b = __builtin_bit_cast(u32, x);
    b += 0x7FFFu + ((b >> 16) & 1u);
    return (u16)(b >> 16);
}
__device__ __forceinline__ float bf2f(u16 u) {
    u32 b = ((u32)u) << 16;
    return __builtin_bit_cast(float, b);
}

// Swizzled tiled plane address, in 16-byte units.
// Plane layout: [row/128][c/64] tiles of 1024 units;
// unit-in-tile = (row&127)*8 + (slot ^ (row&7)), slot = (c&63)>>3.
__device__ __forceinline__ size_t sw_unit(int row, int c, int CC) {
    int slot = (c & 63) >> 3;
    return ((size_t)((row >> 7) * CC + (c >> 6)) << 10)
         + (size_t)((row & 127) << 3) + (size_t)(slot ^ (row & 7));
}

// ---------------------------------------------------------------------------
// prep: activations -> swizzled hi/lo planes; weights -> hi only (proj) or
// hi+lo (Wfuse). Dropping proj W-lo is the R9-validated 2-term split
// (absmax 9.77e-4 measured).
// ---------------------------------------------------------------------------
__device__ void prep_x(const float* __restrict__ X, int C, int HW, int bl, int PT,
                       u16* __restrict__ dh, u16* __restrict__ dl) {
    __shared__ float Xt[64][65];
    const int t = threadIdx.x;
    const int pt = bl % PT, ct = bl / PT;
    const int p0 = pt * 64, c0 = ct * 64;
    const int b = p0 / HW, hw0 = p0 % HW;
    #pragma unroll
    for (int i = 0; i < 16; i++) {
        int r = (t >> 6) + i * 4;
        Xt[r][t & 63] = X[(size_t)(b * C + c0 + r) * HW + hw0 + (t & 63)];
    }
    __syncthreads();
    const int CC = C >> 6;
    #pragma unroll
    for (int it = 0; it < 2; it++) {
        int id = t + it * 256;
        int px = id >> 3, sl = id & 7;
        bf16x8 hv, lv;
        #pragma unroll
        for (int j = 0; j < 8; j++) {
            float x = Xt[sl * 8 + j][px];
            u16 h = f2bf(x);
            hv[j] = (short)h;
            lv[j] = (short)f2bf(x - bf2f(h));
        }
        size_t unit = sw_unit(p0 + px, c0 + sl * 8, CC);
        *(bf16x8*)(dh + unit * 8) = hv;
        *(bf16x8*)(dl + unit * 8) = lv;
    }
}

__device__ void prep_w(const float* __restrict__ W, int C, int bl,
                       u16* __restrict__ dh, u16* __restrict__ dl, bool wlo) {
    const int t = threadIdx.x;
    const int ot = bl & 3, cc = bl >> 2;
    const int o0 = ot * 64, c0 = cc * 64;
    const int CC = C >> 6;
    #pragma unroll
    for (int it = 0; it < 2; it++) {
        int id = t + it * 256;
        int ol = id >> 3, sl = id & 7;
        int o = o0 + ol, c = c0 + sl * 8;
        const float* wp = W + (size_t)o * C + c;
        float4 a = *(const float4*)wp;
        float4 b2 = *(const float4*)(wp + 4);
        float xs[8] = {a.x, a.y, a.z, a.w, b2.x, b2.y, b2.z, b2.w};
        bf16x8 hv, lv;
        #pragma unroll
        for (int j = 0; j < 8; j++) {
            u16 h = f2bf(xs[j]);
            hv[j] = (short)h;
            lv[j] = (short)f2bf(xs[j] - bf2f(h));
        }
        size_t unit = sw_unit(o, c, CC);
        *(bf16x8*)(dh + unit * 8) = hv;
        if (wlo) *(bf16x8*)(dl + unit * 8) = lv;
    }
}

// W plane offsets (u16 units) inside Whi/Wlo
#define OFF_WQ 0
#define OFF_WK0 65536
#define OFF_WV0 163840
#define OFF_WK1 262144
#define OFF_WV1 458752
#define OFF_WFUSE 655360

__global__ __launch_bounds__(256) void prep_k(
    const float* __restrict__ query, const float* __restrict__ mem0, const float* __restrict__ mem1,
    const float* __restrict__ Wq, const float* __restrict__ Wk0, const float* __restrict__ Wv0,
    const float* __restrict__ Wk1, const float* __restrict__ Wv1, const float* __restrict__ Wfuse,
    u16* Xq_hi, u16* Xq_lo, u16* Xm0_hi, u16* Xm0_lo, u16* Xm1_hi, u16* Xm1_lo,
    u16* Whi, u16* Wlo)
{
    const int bx = blockIdx.x;
    if (bx < 512)      prep_x(query, 256, 4096, bx,       128, Xq_hi, Xq_lo);
    else if (bx < 704) prep_x(mem0,  384, 1024, bx - 512,  32, Xm0_hi, Xm0_lo);
    else if (bx < 800) prep_x(mem1,  768,  256, bx - 704,   8, Xm1_hi, Xm1_lo);
    else {
        int r = bx - 800;
        if (r < 16)       prep_w(Wq,    256, r,       Whi + OFF_WQ,    Wlo, false);
        else if (r < 40)  prep_w(Wk0,   384, r - 16,  Whi + OFF_WK0,   Wlo, false);
        else if (r < 64)  prep_w(Wv0,   384, r - 40,  Whi + OFF_WV0,   Wlo, false);
        else if (r < 112) prep_w(Wk1,   768, r - 64,  Whi + OFF_WK1,   Wlo, false);
        else if (r < 160) prep_w(Wv1,   768, r - 112, Whi + OFF_WV1,   Wlo, false);
        else              prep_w(Wfuse, 512, r - 160, Whi + OFF_WFUSE, Wlo + OFF_WFUSE, true);
    }
}

// ---------------------------------------------------------------------------
// 2-term split MFMA GEMM core: D = Ahi·Bhi + Alo·Bhi (+bias).
// Block 128x128, 4 waves of 64x64 (4x4 16x16 D-tiles), KC=64, 3 LDS planes
// (48 KB), 2-phase pipelined staging (R8-proven).
// OUT16=true: Y u16 pixel-major [row][256]. false: f32 channel-major out.
// ---------------------------------------------------------------------------
template<bool OUT16>
__device__ __forceinline__ void gemm_core(
    const u16* __restrict__ Ahi, const u16* __restrict__ Alo,
    const u16* __restrict__ Bhi, const float* __restrict__ bias,
    void* __restrict__ Y, int CC, int am, int bn, u16* smem)
{
    const int t = threadIdx.x, lane = t & 63, w = t >> 6;
    const int wr = w >> 1, wc = w & 1;
    const int l15 = lane & 15;

    f32x4 acc[4][4];
    #pragma unroll
    for (int a = 0; a < 4; a++)
        #pragma unroll
        for (int b2 = 0; b2 < 4; b2++)
            acc[a][b2] = (f32x4){0.f, 0.f, 0.f, 0.f};

    bf16x8 stg[3][4];
    // ---- prologue: load chunk 0 ----
    {
        const size_t aoff = ((size_t)(am * CC)) << 13;
        const size_t boff = ((size_t)(bn * CC)) << 13;
        #pragma unroll
        for (int it = 0; it < 4; it++) {
            const size_t o = (size_t)(t + it * 256) * 8;
            stg[0][it] = *(const bf16x8*)(Ahi + aoff + o);
            stg[1][it] = *(const bf16x8*)(Alo + aoff + o);
            stg[2][it] = *(const bf16x8*)(Bhi + boff + o);
        }
    }

    for (int ck = 0; ck < CC; ck++) {
        __syncthreads();   // prior chunk's LDS reads done
        #pragma unroll
        for (int p = 0; p < 3; p++)
            #pragma unroll
            for (int it = 0; it < 4; it++)
                *(bf16x8*)(smem + p * 8192 + (size_t)(t + it * 256) * 8) = stg[p][it];
        __syncthreads();   // chunk staged

        // ---- prefetch next chunk (clamped; last-iter re-read harmless) ----
        {
            const int cn = (ck + 1 < CC) ? ck + 1 : ck;
            const size_t aoff = ((size_t)(am * CC + cn)) << 13;
            const size_t boff = ((size_t)(bn * CC + cn)) << 13;
            #pragma unroll
            for (int it = 0; it < 4; it++) {
                const size_t o = (size_t)(t + it * 256) * 8;
                stg[0][it] = *(const bf16x8*)(Ahi + aoff + o);
                stg[1][it] = *(const bf16x8*)(Alo + aoff + o);
                stg[2][it] = *(const bf16x8*)(Bhi + boff + o);
            }
        }

        // ---- compute: 2 k-steps of 32 ----
        #pragma unroll
        for (int kk = 0; kk < 2; kk++) {
            bf16x8 ah[4], al[4], bh[4];
            #pragma unroll
            for (int tr = 0; tr < 4; tr++) {
                int row = wr * 64 + tr * 16 + l15;
                int off = row * 64 + (((kk * 4 + (lane >> 4)) ^ (row & 7)) << 3);
                ah[tr] = *(const bf16x8*)(smem + off);
                al[tr] = *(const bf16x8*)(smem + 8192 + off);
            }
            #pragma unroll
            for (int tc = 0; tc < 4; tc++) {
                int row = wc * 64 + tc * 16 + l15;
                int off = row * 64 + (((kk * 4 + (lane >> 4)) ^ (row & 7)) << 3);
                bh[tc] = *(const bf16x8*)(smem + 16384 + off);
            }
            #pragma unroll
            for (int tr = 0; tr < 4; tr++)
                #pragma unroll
                for (int tc = 0; tc < 4; tc++) {
                    acc[tr][tc] = __builtin_amdgcn_mfma_f32_16x16x32_bf16(ah[tr], bh[tc], acc[tr][tc], 0, 0, 0);
                    acc[tr][tc] = __builtin_amdgcn_mfma_f32_16x16x32_bf16(al[tr], bh[tc], acc[tr][tc], 0, 0, 0);
                }
        }
    }

    // ---- epilogue: D row = (lane>>4)*4+i, col = l15 (m89-verified) ----
    if (OUT16) {
        u16* Y16 = (u16*)Y;
        float bv[4];
        #pragma unroll
        for (int tc = 0; tc < 4; tc++)
            bv[tc] = bias[bn * 128 + wc * 64 + tc * 16 + l15];
        #pragma unroll
        for (int tr = 0; tr < 4; tr++) {
            #pragma unroll
            for (int i = 0; i < 4; i++) {
                int rp = am * 128 + wr * 64 + tr * 16 + ((lane >> 4) << 2) + i;
                u16* yr = Y16 + (size_t)rp * 256 + bn * 128 + wc * 64 + l15;
                #pragma unroll
                for (int tc = 0; tc < 4; tc++)
                    yr[tc * 16] = f2bf(acc[tr][tc][i] + bv[tc]);
            }
        }
    } else {
        float* Yf = (float*)Y;
        #pragma unroll
        for (int tr = 0; tr < 4; tr++) {
            #pragma unroll
            for (int i = 0; i < 4; i++) {
                int o = am * 128 + wr * 64 + tr * 16 + ((lane >> 4) << 2) + i;
                float bv = bias[o];
                #pragma unroll
                for (int tc = 0; tc < 4; tc++) {
                    int pcol = bn * 128 + wc * 64 + tc * 16 + l15;
                    Yf[(size_t)((pcol >> 12) * 256 + o) * 4096 + (pcol & 4095)] = acc[tr][tc][i] + bv;
                }
            }
        }
    }
}

// proj: q / k0 / v0 / k1 / v1 in one 208-block dispatch (2-term split)
__global__ __launch_bounds__(256) void projmm_k(
    const u16* __restrict__ Xq_hi, const u16* __restrict__ Xq_lo,
    const u16* __restrict__ Xm0_hi, const u16* __restrict__ Xm0_lo,
    const u16* __restrict__ Xm1_hi, const u16* __restrict__ Xm1_lo,
    const u16* __restrict__ Whi,
    const float* __restrict__ bq, const float* __restrict__ bk0, const float* __restrict__ bv0,
    const float* __restrict__ bk1, const float* __restrict__ bv1,
    u16* qT, u16* k0T, u16* v0T, u16* k1T, u16* v1T)
{
    __shared__ u16 smem[24576];   // 48 KB
    const int bx = blockIdx.x;
    if (bx < 128) {
        gemm_core<true>(Xq_hi, Xq_lo, Whi + OFF_WQ, bq, (void*)qT, 4, bx >> 1, bx & 1, smem);
    } else if (bx < 192) {
        const int r = bx - 128, am = r >> 2, bnn = r & 3;
        if (bnn < 2) gemm_core<true>(Xm0_hi, Xm0_lo, Whi + OFF_WK0, bk0, (void*)k0T, 6, am, bnn, smem);
        else         gemm_core<true>(Xm0_hi, Xm0_lo, Whi + OFF_WV0, bv0, (void*)v0T, 6, am, bnn - 2, smem);
    } else {
        const int r = bx - 192, am = r >> 2, bnn = r & 3;
        if (bnn < 2) gemm_core<true>(Xm1_hi, Xm1_lo, Whi + OFF_WK1, bk1, (void*)k1T, 12, am, bnn, smem);
        else         gemm_core<true>(Xm1_hi, Xm1_lo, Whi + OFF_WV1, bv1, (void*)v1T, 12, am, bnn - 2, smem);
    }
}

// fuse: out = Wfuse·fused + bfuse; A = Whi/Wlo split, B = fused hi plane
__global__ __launch_bounds__(256) void fusemm_k(
    const u16* __restrict__ Whi, const u16* __restrict__ Wlo,
    const u16* __restrict__ fhi, const float* __restrict__ bfuse, float* out)
{
    __shared__ u16 smem[24576];
    const int bx = blockIdx.x;
    gemm_core<false>(Whi + OFF_WFUSE, Wlo + OFF_WFUSE, fhi, bfuse, (void*)out,
                     8, bx & 1, bx >> 1, smem);
}

// ---------------------------------------------------------------------------
// MFMA attention (R5/R8-proven, unchanged). One wave per (b, head, 4x4
// q-tile); 8x8 candidate superset, mask to window+borders; S = Q·K^T, wave
// softmax, P->LDS, O = P·V with clamped scalar V-gather.
// ---------------------------------------------------------------------------
template<int SCALE>
__device__ __forceinline__ void attn_mfma(
    const u16* __restrict__ qT, const u16* __restrict__ kT,
    const u16* __restrict__ vT, u16* __restrict__ fhi,
    int b, int n, int ty, int tx, int lane, u16* s_lds)
{
    constexpr int HM = SCALE ? 16 : 32;
    const int qy0 = ty * 4, qx0 = tx * 4;
    const int ay0 = SCALE ? (qy0 >> 2) : (qy0 >> 1);
    const int ax0 = SCALE ? (qx0 >> 2) : (qx0 >> 1);
    const int l15 = lane & 15, kg = lane >> 4;

    const int pA = (b * 64 + qy0 + (l15 >> 2)) * 64 + qx0 + (l15 & 3);
    const bf16x8 qf = *(const bf16x8*)(qT + (size_t)pA * 256 + n * 32 + kg * 8);

    f32x4 s[4];
    #pragma unroll
    for (int t = 0; t < 4; t++) {
        const int cand = t * 16 + l15;
        const int wy = cand >> 3, wx = cand & 7;
        const int my = SCALE ? (ay0 + (wy - 2) * 2) : (ay0 - 3 + wy);
        const int mx = SCALE ? (ax0 + (wx - 2) * 2) : (ax0 - 3 + wx);
        const int myc = min(max(my, 0), HM - 1), mxc = min(max(mx, 0), HM - 1);
        const bf16x8 kf = *(const bf16x8*)(kT + (size_t)((b * HM + myc) * HM + mxc) * 256 + n * 32 + kg * 8);
        s[t] = __builtin_amdgcn_mfma_f32_16x16x32_bf16(qf, kf, (f32x4){0.f, 0.f, 0.f, 0.f}, 0, 0, 0);
    }

    const float scl = 0.17677669529663687f;
    float sv[4][4];
    #pragma unroll
    for (int t = 0; t < 4; t++) {
        const int cand = t * 16 + l15;
        const int wy = cand >> 3, wx = cand & 7;
        const int my = SCALE ? (ay0 + (wy - 2) * 2) : (ay0 - 3 + wy);
        const int mx = SCALE ? (ax0 + (wx - 2) * 2) : (ax0 - 3 + wx);
        const bool inb = (my >= 0) && (my < HM) && (mx >= 0) && (mx < HM);
        #pragma unroll
        for (int i = 0; i < 4; i++) {
            bool ok;
            if (SCALE) {
                ok = inb && (wy < 5) && (wx < 5);
            } else {
                const int r = kg * 4 + i;
                const int dy2 = (r >> 2) >> 1, dx2 = (r & 3) >> 1;
                ok = inb && ((u32)(wy - dy2) <= 6u) && ((u32)(wx - dx2) <= 6u);
            }
            sv[t][i] = ok ? s[t][i] * scl : -1e30f;
        }
    }

    float linv[4];
    #pragma unroll
    for (int i = 0; i < 4; i++) {
        float m = fmaxf(fmaxf(sv[0][i], sv[1][i]), fmaxf(sv[2][i], sv[3][i]));
        #pragma unroll
        for (int dd = 1; dd < 16; dd <<= 1) m = fmaxf(m, __shfl_xor(m, dd, 64));
        float l = 0.f;
        #pragma unroll
        for (int t = 0; t < 4; t++) { sv[t][i] = __expf(sv[t][i] - m); l += sv[t][i]; }
        #pragma unroll
        for (int dd = 1; dd < 16; dd <<= 1) l += __shfl_xor(l, dd, 64);
        linv[i] = 1.f / l;
    }

    #pragma unroll
    for (int t = 0; t < 4; t++)
        #pragma unroll
        for (int i = 0; i < 4; i++)
            s_lds[(kg * 4 + i) * 68 + t * 16 + l15] = f2bf(sv[t][i]);
    __syncthreads();

    f32x4 o[2] = {(f32x4){0.f,0.f,0.f,0.f}, (f32x4){0.f,0.f,0.f,0.f}};
    #pragma unroll
    for (int h = 0; h < 2; h++) {
        const bf16x8 pa = *(const bf16x8*)(s_lds + l15 * 68 + h * 32 + kg * 8);
        #pragma unroll
        for (int c = 0; c < 2; c++) {
            bf16x8 vf;
            #pragma unroll
            for (int j = 0; j < 8; j++) {
                const int cand = h * 32 + kg * 8 + j;
                const int wy = cand >> 3, wx = cand & 7;
                int my = SCALE ? (ay0 + (wy - 2) * 2) : (ay0 - 3 + wy);
                int mx = SCALE ? (ax0 + (wx - 2) * 2) : (ax0 - 3 + wx);
                my = min(max(my, 0), HM - 1); mx = min(max(mx, 0), HM - 1);
                vf[j] = (short)vT[(size_t)((b * HM + my) * HM + mx) * 256 + n * 32 + c * 16 + l15];
            }
            o[c] = __builtin_amdgcn_mfma_f32_16x16x32_bf16(pa, vf, o[c], 0, 0, 0);
        }
    }

    #pragma unroll
    for (int c = 0; c < 2; c++) {
        #pragma unroll
        for (int i = 0; i < 4; i++) {
            const int r = kg * 4 + i;
            const int p = (b * 64 + qy0 + (r >> 2)) * 64 + qx0 + (r & 3);
            const int ch = (SCALE ? 256 : 0) + n * 32 + c * 16 + l15;
            fhi[sw_unit(p, ch, 8) * 8 + (ch & 7)] = f2bf(o[c][i] * linv[i]);
        }
    }
}

__global__ __launch_bounds__(256) void attn_k(
    const u16* __restrict__ qT,
    const u16* __restrict__ k0T, const u16* __restrict__ v0T,
    const u16* __restrict__ k1T, const u16* __restrict__ v1T,
    u16* __restrict__ fhi)
{
    __shared__ u16 s_lds[4][16 * 68];
    const int t = threadIdx.x, w = t >> 6, lane = t & 63;
    const int bx = blockIdx.x;
    const int sc = bx >> 10;
    const int tile = (bx & 1023) * 4 + w;
    const int b = tile >> 11, n = (tile >> 8) & 7;
    const int ty = (tile >> 4) & 15, tx = tile & 15;
    if (sc == 0) attn_mfma<0>(qT, k0T, v0T, fhi, b, n, ty, tx, lane, s_lds[w]);
    else         attn_mfma<1>(qT, k1T, v1T, fhi, b, n, ty, tx, lane, s_lds[w]);
}

// ---------------------------------------------------------------------------
extern "C" void kernel_launch(void* const* d_in, const int* in_sizes, int n_in,
                              void* d_out, int out_size, void* d_ws, size_t ws_size,
                              hipStream_t stream)
{
    const float* query = (const float*)d_in[0];
    const float* mem0  = (const float*)d_in[1];
    const float* mem1  = (const float*)d_in[2];
    const float* Wq    = (const float*)d_in[3];  const float* bq    = (const float*)d_in[4];
    const float* Wk0   = (const float*)d_in[5];  const float* bk0   = (const float*)d_in[6];
    const float* Wv0   = (const float*)d_in[7];  const float* bv0   = (const float*)d_in[8];
    const float* Wk1   = (const float*)d_in[9];  const float* bk1   = (const float*)d_in[10];
    const float* Wv1   = (const float*)d_in[11]; const float* bv1   = (const float*)d_in[12];
    const float* Wfuse = (const float*)d_in[13]; const float* bfuse = (const float*)d_in[14];
    float* out = (float*)d_out;

    char* ws = (char*)d_ws;
    u16* qT       = (u16*)(ws + 0);            // 4 MB (bf16 pixel-major)
    u16* k0T      = (u16*)(ws + 8388608);      // 1 MB
    u16* v0T      = (u16*)(ws + 10485760);     // 1 MB
    u16* k1T      = (u16*)(ws + 12582912);     // 256 KB
    u16* v1T      = (u16*)(ws + 13107200);     // 256 KB
    u16* Whi      = (u16*)(ws + 13631488);
    u16* Wlo      = (u16*)(ws + 15204352);
    u16* Xm0_hi   = (u16*)(ws + 16777216);
    u16* Xm0_lo   = (u16*)(ws + 18350080);
    u16* Xm1_hi   = (u16*)(ws + 19922944);
    u16* Xm1_lo   = (u16*)(ws + 20709376);
    u16* Xq_hi    = (u16*)(ws + 21495808);     // 4 MB
    u16* Xq_lo    = (u16*)(ws + 25690112);     // 4 MB
    u16* fhi      = Xq_hi;                     // fused plane aliases Xq planes

    prep_k<<<dim3(992), 256, 0, stream>>>(
        query, mem0, mem1, Wq, Wk0, Wv0, Wk1, Wv1, Wfuse,
        Xq_hi, Xq_lo, Xm0_hi, Xm0_lo, Xm1_hi, Xm1_lo, Whi, Wlo);

    projmm_k<<<dim3(208), 256, 0, stream>>>(
        Xq_hi, Xq_lo, Xm0_hi, Xm0_lo, Xm1_hi, Xm1_lo, Whi,
        bq, bk0, bv0, bk1, bv1, qT, k0T, v0T, k1T, v1T);

    attn_k<<<dim3(2048), 256, 0, stream>>>(qT, k0T, v0T, k1T, v1T, fhi);

    fusemm_k<<<dim3(128), 256, 0, stream>>>(Whi, Wlo, fhi, bfuse, out);
}

// Round 12
// 56.037 us; speedup vs baseline: 1.3243x; 1.1373x over previous
//
#include <hip/hip_runtime.h>
#include <math.h>

typedef unsigned short u16;
typedef unsigned int u32;
typedef __attribute__((ext_vector_type(8))) short bf16x8;
typedef __attribute__((ext_vector_type(4))) float f32x4;

// ---------------- bf16 helpers (manual RNE; inputs are finite) ----------------
__device__ __forceinline__ u16 f2bf(float x) {
    u32 b = __builtin_bit_cast(u32, x);
    b += 0x7FFFu + ((b >> 16) & 1u);
    return (u16)(b >> 16);
}
__device__ __forceinline__ float bf2f(u16 u) {
    u32 b = ((u32)u) << 16;
    return __builtin_bit_cast(float, b);
}

// Swizzled tiled plane address, in 16-byte units.
// Plane layout: [row/128][c/64] tiles of 1024 units;
// unit-in-tile = (row&127)*8 + (slot ^ (row&7)), slot = (c&63)>>3.
__device__ __forceinline__ size_t sw_unit(int row, int c, int CC) {
    int slot = (c & 63) >> 3;
    return ((size_t)((row >> 7) * CC + (c >> 6)) << 10)
         + (size_t)((row & 127) << 3) + (size_t)(slot ^ (row & 7));
}

// ---------------------------------------------------------------------------
// prep: activations -> swizzled bf16 HI planes only (X_lo measured to not
// move absmax: R9 vs R10 both 9.77e-4). Weights: hi only (proj), hi+lo (Wfuse).
// ---------------------------------------------------------------------------
__device__ void prep_x(const float* __restrict__ X, int C, int HW, int bl, int PT,
                       u16* __restrict__ dh) {
    __shared__ float Xt[64][65];
    const int t = threadIdx.x;
    const int pt = bl % PT, ct = bl / PT;
    const int p0 = pt * 64, c0 = ct * 64;
    const int b = p0 / HW, hw0 = p0 % HW;
    #pragma unroll
    for (int i = 0; i < 16; i++) {
        int r = (t >> 6) + i * 4;
        Xt[r][t & 63] = X[(size_t)(b * C + c0 + r) * HW + hw0 + (t & 63)];
    }
    __syncthreads();
    const int CC = C >> 6;
    #pragma unroll
    for (int it = 0; it < 2; it++) {
        int id = t + it * 256;
        int px = id >> 3, sl = id & 7;
        bf16x8 hv;
        #pragma unroll
        for (int j = 0; j < 8; j++)
            hv[j] = (short)f2bf(Xt[sl * 8 + j][px]);
        size_t unit = sw_unit(p0 + px, c0 + sl * 8, CC);
        *(bf16x8*)(dh + unit * 8) = hv;
    }
}

__device__ void prep_w(const float* __restrict__ W, int C, int bl,
                       u16* __restrict__ dh, u16* __restrict__ dl, bool wlo) {
    const int t = threadIdx.x;
    const int ot = bl & 3, cc = bl >> 2;
    const int o0 = ot * 64, c0 = cc * 64;
    const int CC = C >> 6;
    #pragma unroll
    for (int it = 0; it < 2; it++) {
        int id = t + it * 256;
        int ol = id >> 3, sl = id & 7;
        int o = o0 + ol, c = c0 + sl * 8;
        const float* wp = W + (size_t)o * C + c;
        float4 a = *(const float4*)wp;
        float4 b2 = *(const float4*)(wp + 4);
        float xs[8] = {a.x, a.y, a.z, a.w, b2.x, b2.y, b2.z, b2.w};
        bf16x8 hv, lv;
        #pragma unroll
        for (int j = 0; j < 8; j++) {
            u16 h = f2bf(xs[j]);
            hv[j] = (short)h;
            lv[j] = (short)f2bf(xs[j] - bf2f(h));
        }
        size_t unit = sw_unit(o, c, CC);
        *(bf16x8*)(dh + unit * 8) = hv;
        if (wlo) *(bf16x8*)(dl + unit * 8) = lv;
    }
}

// W plane offsets (u16 units) inside Whi/Wlo
#define OFF_WQ 0
#define OFF_WK0 65536
#define OFF_WV0 163840
#define OFF_WK1 262144
#define OFF_WV1 458752
#define OFF_WFUSE 655360

__global__ __launch_bounds__(256) void prep_k(
    const float* __restrict__ query, const float* __restrict__ mem0, const float* __restrict__ mem1,
    const float* __restrict__ Wq, const float* __restrict__ Wk0, const float* __restrict__ Wv0,
    const float* __restrict__ Wk1, const float* __restrict__ Wv1, const float* __restrict__ Wfuse,
    u16* Xq_hi, u16* Xm0_hi, u16* Xm1_hi, u16* Whi, u16* Wlo)
{
    const int bx = blockIdx.x;
    if (bx < 512)      prep_x(query, 256, 4096, bx,       128, Xq_hi);
    else if (bx < 704) prep_x(mem0,  384, 1024, bx - 512,  32, Xm0_hi);
    else if (bx < 800) prep_x(mem1,  768,  256, bx - 704,   8, Xm1_hi);
    else {
        int r = bx - 800;
        if (r < 16)       prep_w(Wq,    256, r,       Whi + OFF_WQ,    Wlo, false);
        else if (r < 40)  prep_w(Wk0,   384, r - 16,  Whi + OFF_WK0,   Wlo, false);
        else if (r < 64)  prep_w(Wv0,   384, r - 40,  Whi + OFF_WV0,   Wlo, false);
        else if (r < 112) prep_w(Wk1,   768, r - 64,  Whi + OFF_WK1,   Wlo, false);
        else if (r < 160) prep_w(Wv1,   768, r - 112, Whi + OFF_WV1,   Wlo, false);
        else              prep_w(Wfuse, 512, r - 160, Whi + OFF_WFUSE, Wlo + OFF_WFUSE, true);
    }
}

// ---------------------------------------------------------------------------
// MFMA GEMM core. TERMS=1: D = Ahi·Bhi (pure bf16, 2 LDS planes, 32 KB).
// TERMS=2: D = Ahi·Bhi + Alo·Bhi (3 planes, 48 KB).
// Block 128x128, 4 waves of 64x64 (4x4 16x16 D-tiles), KC=64, 2-phase
// pipelined staging (R8-proven).
// OUT16=true: Y u16 pixel-major [row][256]. false: f32 channel-major out.
// ---------------------------------------------------------------------------
template<int TERMS, bool OUT16>
__device__ __forceinline__ void gemm_core(
    const u16* __restrict__ Ahi, const u16* __restrict__ Alo,
    const u16* __restrict__ Bhi, const float* __restrict__ bias,
    void* __restrict__ Y, int CC, int am, int bn, u16* smem)
{
    const int t = threadIdx.x, lane = t & 63, w = t >> 6;
    const int wr = w >> 1, wc = w & 1;
    const int l15 = lane & 15;

    f32x4 acc[4][4];
    #pragma unroll
    for (int a = 0; a < 4; a++)
        #pragma unroll
        for (int b2 = 0; b2 < 4; b2++)
            acc[a][b2] = (f32x4){0.f, 0.f, 0.f, 0.f};

    bf16x8 stg[TERMS + 1][4];
    // ---- prologue: load chunk 0 ----
    {
        const size_t aoff = ((size_t)(am * CC)) << 13;
        const size_t boff = ((size_t)(bn * CC)) << 13;
        #pragma unroll
        for (int it = 0; it < 4; it++) {
            const size_t o = (size_t)(t + it * 256) * 8;
            stg[0][it] = *(const bf16x8*)(Ahi + aoff + o);
            if constexpr (TERMS == 2) stg[1][it] = *(const bf16x8*)(Alo + aoff + o);
            stg[TERMS][it] = *(const bf16x8*)(Bhi + boff + o);
        }
    }

    for (int ck = 0; ck < CC; ck++) {
        __syncthreads();   // prior chunk's LDS reads done
        #pragma unroll
        for (int p = 0; p <= TERMS; p++)
            #pragma unroll
            for (int it = 0; it < 4; it++)
                *(bf16x8*)(smem + p * 8192 + (size_t)(t + it * 256) * 8) = stg[p][it];
        __syncthreads();   // chunk staged

        // ---- prefetch next chunk (clamped; last-iter re-read harmless) ----
        {
            const int cn = (ck + 1 < CC) ? ck + 1 : ck;
            const size_t aoff = ((size_t)(am * CC + cn)) << 13;
            const size_t boff = ((size_t)(bn * CC + cn)) << 13;
            #pragma unroll
            for (int it = 0; it < 4; it++) {
                const size_t o = (size_t)(t + it * 256) * 8;
                stg[0][it] = *(const bf16x8*)(Ahi + aoff + o);
                if constexpr (TERMS == 2) stg[1][it] = *(const bf16x8*)(Alo + aoff + o);
                stg[TERMS][it] = *(const bf16x8*)(Bhi + boff + o);
            }
        }

        // ---- compute: 2 k-steps of 32 ----
        #pragma unroll
        for (int kk = 0; kk < 2; kk++) {
            bf16x8 ah[4], al[4], bh[4];
            #pragma unroll
            for (int tr = 0; tr < 4; tr++) {
                int row = wr * 64 + tr * 16 + l15;
                int off = row * 64 + (((kk * 4 + (lane >> 4)) ^ (row & 7)) << 3);
                ah[tr] = *(const bf16x8*)(smem + off);
                if constexpr (TERMS == 2) al[tr] = *(const bf16x8*)(smem + 8192 + off);
            }
            #pragma unroll
            for (int tc = 0; tc < 4; tc++) {
                int row = wc * 64 + tc * 16 + l15;
                int off = row * 64 + (((kk * 4 + (lane >> 4)) ^ (row & 7)) << 3);
                bh[tc] = *(const bf16x8*)(smem + TERMS * 8192 + off);
            }
            #pragma unroll
            for (int tr = 0; tr < 4; tr++)
                #pragma unroll
                for (int tc = 0; tc < 4; tc++) {
                    acc[tr][tc] = __builtin_amdgcn_mfma_f32_16x16x32_bf16(ah[tr], bh[tc], acc[tr][tc], 0, 0, 0);
                    if constexpr (TERMS == 2)
                        acc[tr][tc] = __builtin_amdgcn_mfma_f32_16x16x32_bf16(al[tr], bh[tc], acc[tr][tc], 0, 0, 0);
                }
        }
    }

    // ---- epilogue: D row = (lane>>4)*4+i, col = l15 (m89-verified) ----
    if (OUT16) {
        u16* Y16 = (u16*)Y;
        float bv[4];
        #pragma unroll
        for (int tc = 0; tc < 4; tc++)
            bv[tc] = bias[bn * 128 + wc * 64 + tc * 16 + l15];
        #pragma unroll
        for (int tr = 0; tr < 4; tr++) {
            #pragma unroll
            for (int i = 0; i < 4; i++) {
                int rp = am * 128 + wr * 64 + tr * 16 + ((lane >> 4) << 2) + i;
                u16* yr = Y16 + (size_t)rp * 256 + bn * 128 + wc * 64 + l15;
                #pragma unroll
                for (int tc = 0; tc < 4; tc++)
                    yr[tc * 16] = f2bf(acc[tr][tc][i] + bv[tc]);
            }
        }
    } else {
        float* Yf = (float*)Y;
        #pragma unroll
        for (int tr = 0; tr < 4; tr++) {
            #pragma unroll
            for (int i = 0; i < 4; i++) {
                int o = am * 128 + wr * 64 + tr * 16 + ((lane >> 4) << 2) + i;
                float bv = bias[o];
                #pragma unroll
                for (int tc = 0; tc < 4; tc++) {
                    int pcol = bn * 128 + wc * 64 + tc * 16 + l15;
                    Yf[(size_t)((pcol >> 12) * 256 + o) * 4096 + (pcol & 4095)] = acc[tr][tc][i] + bv;
                }
            }
        }
    }
}

// proj: q / k0 / v0 / k1 / v1 in one 208-block dispatch (1-term bf16)
__global__ __launch_bounds__(256) void projmm_k(
    const u16* __restrict__ Xq_hi, const u16* __restrict__ Xm0_hi,
    const u16* __restrict__ Xm1_hi, const u16* __restrict__ Whi,
    const float* __restrict__ bq, const float* __restrict__ bk0, const float* __restrict__ bv0,
    const float* __restrict__ bk1, const float* __restrict__ bv1,
    u16* qT, u16* k0T, u16* v0T, u16* k1T, u16* v1T)
{
    __shared__ u16 smem[16384];   // 32 KB
    const int bx = blockIdx.x;
    if (bx < 128) {
        gemm_core<1, true>(Xq_hi, nullptr, Whi + OFF_WQ, bq, (void*)qT, 4, bx >> 1, bx & 1, smem);
    } else if (bx < 192) {
        const int r = bx - 128, am = r >> 2, bnn = r & 3;
        if (bnn < 2) gemm_core<1, true>(Xm0_hi, nullptr, Whi + OFF_WK0, bk0, (void*)k0T, 6, am, bnn, smem);
        else         gemm_core<1, true>(Xm0_hi, nullptr, Whi + OFF_WV0, bv0, (void*)v0T, 6, am, bnn - 2, smem);
    } else {
        const int r = bx - 192, am = r >> 2, bnn = r & 3;
        if (bnn < 2) gemm_core<1, true>(Xm1_hi, nullptr, Whi + OFF_WK1, bk1, (void*)k1T, 12, am, bnn, smem);
        else         gemm_core<1, true>(Xm1_hi, nullptr, Whi + OFF_WV1, bv1, (void*)v1T, 12, am, bnn - 2, smem);
    }
}

// fuse: out = Wfuse·fused + bfuse; A = Whi/Wlo 2-term split, B = fused hi plane
__global__ __launch_bounds__(256) void fusemm_k(
    const u16* __restrict__ Whi, const u16* __restrict__ Wlo,
    const u16* __restrict__ fhi, const float* __restrict__ bfuse, float* out)
{
    __shared__ u16 smem[24576];   // 48 KB
    const int bx = blockIdx.x;
    gemm_core<2, false>(Whi + OFF_WFUSE, Wlo + OFF_WFUSE, fhi, bfuse, (void*)out,
                        8, bx & 1, bx >> 1, smem);
}

// ---------------------------------------------------------------------------
// MFMA attention (R5/R8/R10-proven, unchanged). One wave per (b, head, 4x4
// q-tile); 8x8 candidate superset, mask to window+borders; S = Q·K^T, wave
// softmax, P->LDS, O = P·V with clamped scalar V-gather.
// ---------------------------------------------------------------------------
template<int SCALE>
__device__ __forceinline__ void attn_mfma(
    const u16* __restrict__ qT, const u16* __restrict__ kT,
    const u16* __restrict__ vT, u16* __restrict__ fhi,
    int b, int n, int ty, int tx, int lane, u16* s_lds)
{
    constexpr int HM = SCALE ? 16 : 32;
    const int qy0 = ty * 4, qx0 = tx * 4;
    const int ay0 = SCALE ? (qy0 >> 2) : (qy0 >> 1);
    const int ax0 = SCALE ? (qx0 >> 2) : (qx0 >> 1);
    const int l15 = lane & 15, kg = lane >> 4;

    const int pA = (b * 64 + qy0 + (l15 >> 2)) * 64 + qx0 + (l15 & 3);
    const bf16x8 qf = *(const bf16x8*)(qT + (size_t)pA * 256 + n * 32 + kg * 8);

    f32x4 s[4];
    #pragma unroll
    for (int t = 0; t < 4; t++) {
        const int cand = t * 16 + l15;
        const int wy = cand >> 3, wx = cand & 7;
        const int my = SCALE ? (ay0 + (wy - 2) * 2) : (ay0 - 3 + wy);
        const int mx = SCALE ? (ax0 + (wx - 2) * 2) : (ax0 - 3 + wx);
        const int myc = min(max(my, 0), HM - 1), mxc = min(max(mx, 0), HM - 1);
        const bf16x8 kf = *(const bf16x8*)(kT + (size_t)((b * HM + myc) * HM + mxc) * 256 + n * 32 + kg * 8);
        s[t] = __builtin_amdgcn_mfma_f32_16x16x32_bf16(qf, kf, (f32x4){0.f, 0.f, 0.f, 0.f}, 0, 0, 0);
    }

    const float scl = 0.17677669529663687f;
    float sv[4][4];
    #pragma unroll
    for (int t = 0; t < 4; t++) {
        const int cand = t * 16 + l15;
        const int wy = cand >> 3, wx = cand & 7;
        const int my = SCALE ? (ay0 + (wy - 2) * 2) : (ay0 - 3 + wy);
        const int mx = SCALE ? (ax0 + (wx - 2) * 2) : (ax0 - 3 + wx);
        const bool inb = (my >= 0) && (my < HM) && (mx >= 0) && (mx < HM);
        #pragma unroll
        for (int i = 0; i < 4; i++) {
            bool ok;
            if (SCALE) {
                ok = inb && (wy < 5) && (wx < 5);
            } else {
                const int r = kg * 4 + i;
                const int dy2 = (r >> 2) >> 1, dx2 = (r & 3) >> 1;
                ok = inb && ((u32)(wy - dy2) <= 6u) && ((u32)(wx - dx2) <= 6u);
            }
            sv[t][i] = ok ? s[t][i] * scl : -1e30f;
        }
    }

    float linv[4];
    #pragma unroll
    for (int i = 0; i < 4; i++) {
        float m = fmaxf(fmaxf(sv[0][i], sv[1][i]), fmaxf(sv[2][i], sv[3][i]));
        #pragma unroll
        for (int dd = 1; dd < 16; dd <<= 1) m = fmaxf(m, __shfl_xor(m, dd, 64));
        float l = 0.f;
        #pragma unroll
        for (int t = 0; t < 4; t++) { sv[t][i] = __expf(sv[t][i] - m); l += sv[t][i]; }
        #pragma unroll
        for (int dd = 1; dd < 16; dd <<= 1) l += __shfl_xor(l, dd, 64);
        linv[i] = 1.f / l;
    }

    #pragma unroll
    for (int t = 0; t < 4; t++)
        #pragma unroll
        for (int i = 0; i < 4; i++)
            s_lds[(kg * 4 + i) * 68 + t * 16 + l15] = f2bf(sv[t][i]);
    __syncthreads();

    f32x4 o[2] = {(f32x4){0.f,0.f,0.f,0.f}, (f32x4){0.f,0.f,0.f,0.f}};
    #pragma unroll
    for (int h = 0; h < 2; h++) {
        const bf16x8 pa = *(const bf16x8*)(s_lds + l15 * 68 + h * 32 + kg * 8);
        #pragma unroll
        for (int c = 0; c < 2; c++) {
            bf16x8 vf;
            #pragma unroll
            for (int j = 0; j < 8; j++) {
                const int cand = h * 32 + kg * 8 + j;
                const int wy = cand >> 3, wx = cand & 7;
                int my = SCALE ? (ay0 + (wy - 2) * 2) : (ay0 - 3 + wy);
                int mx = SCALE ? (ax0 + (wx - 2) * 2) : (ax0 - 3 + wx);
                my = min(max(my, 0), HM - 1); mx = min(max(mx, 0), HM - 1);
                vf[j] = (short)vT[(size_t)((b * HM + my) * HM + mx) * 256 + n * 32 + c * 16 + l15];
            }
            o[c] = __builtin_amdgcn_mfma_f32_16x16x32_bf16(pa, vf, o[c], 0, 0, 0);
        }
    }

    #pragma unroll
    for (int c = 0; c < 2; c++) {
        #pragma unroll
        for (int i = 0; i < 4; i++) {
            const int r = kg * 4 + i;
            const int p = (b * 64 + qy0 + (r >> 2)) * 64 + qx0 + (r & 3);
            const int ch = (SCALE ? 256 : 0) + n * 32 + c * 16 + l15;
            fhi[sw_unit(p, ch, 8) * 8 + (ch & 7)] = f2bf(o[c][i] * linv[i]);
        }
    }
}

__global__ __launch_bounds__(256) void attn_k(
    const u16* __restrict__ qT,
    const u16* __restrict__ k0T, const u16* __restrict__ v0T,
    const u16* __restrict__ k1T, const u16* __restrict__ v1T,
    u16* __restrict__ fhi)
{
    __shared__ u16 s_lds[4][16 * 68];
    const int t = threadIdx.x, w = t >> 6, lane = t & 63;
    const int bx = blockIdx.x;
    const int sc = bx >> 10;
    const int tile = (bx & 1023) * 4 + w;
    const int b = tile >> 11, n = (tile >> 8) & 7;
    const int ty = (tile >> 4) & 15, tx = tile & 15;
    if (sc == 0) attn_mfma<0>(qT, k0T, v0T, fhi, b, n, ty, tx, lane, s_lds[w]);
    else         attn_mfma<1>(qT, k1T, v1T, fhi, b, n, ty, tx, lane, s_lds[w]);
}

// ---------------------------------------------------------------------------
extern "C" void kernel_launch(void* const* d_in, const int* in_sizes, int n_in,
                              void* d_out, int out_size, void* d_ws, size_t ws_size,
                              hipStream_t stream)
{
    const float* query = (const float*)d_in[0];
    const float* mem0  = (const float*)d_in[1];
    const float* mem1  = (const float*)d_in[2];
    const float* Wq    = (const float*)d_in[3];  const float* bq    = (const float*)d_in[4];
    const float* Wk0   = (const float*)d_in[5];  const float* bk0   = (const float*)d_in[6];
    const float* Wv0   = (const float*)d_in[7];  const float* bv0   = (const float*)d_in[8];
    const float* Wk1   = (const float*)d_in[9];  const float* bk1   = (const float*)d_in[10];
    const float* Wv1   = (const float*)d_in[11]; const float* bv1   = (const float*)d_in[12];
    const float* Wfuse = (const float*)d_in[13]; const float* bfuse = (const float*)d_in[14];
    float* out = (float*)d_out;

    char* ws = (char*)d_ws;
    u16* qT       = (u16*)(ws + 0);            // 4 MB (bf16 pixel-major)
    u16* k0T      = (u16*)(ws + 8388608);      // 1 MB
    u16* v0T      = (u16*)(ws + 10485760);     // 1 MB
    u16* k1T      = (u16*)(ws + 12582912);     // 256 KB
    u16* v1T      = (u16*)(ws + 13107200);     // 256 KB
    u16* Whi      = (u16*)(ws + 13631488);     // 1.5 MB
    u16* Wlo      = (u16*)(ws + 15204352);     // 1.5 MB (only Wfuse slice used)
    u16* Xm0_hi   = (u16*)(ws + 16777216);     // 1.5 MB
    u16* Xm1_hi   = (u16*)(ws + 19922944);     // 768 KB
    u16* Xq_hi    = (u16*)(ws + 21495808);     // 4 MB
    u16* fhi      = Xq_hi;                     // fused plane (8 MB: Xq_hi + next 4 MB)

    prep_k<<<dim3(992), 256, 0, stream>>>(
        query, mem0, mem1, Wq, Wk0, Wv0, Wk1, Wv1, Wfuse,
        Xq_hi, Xm0_hi, Xm1_hi, Whi, Wlo);

    projmm_k<<<dim3(208), 256, 0, stream>>>(
        Xq_hi, Xm0_hi, Xm1_hi, Whi,
        bq, bk0, bv0, bk1, bv1, qT, k0T, v0T, k1T, v1T);

    attn_k<<<dim3(2048), 256, 0, stream>>>(qT, k0T, v0T, k1T, v1T, fhi);

    fusemm_k<<<dim3(128), 256, 0, stream>>>(Whi, Wlo, fhi, bfuse, out);
}

// Round 13
// 50.214 us; speedup vs baseline: 1.4779x; 1.1160x over previous
//
#include <hip/hip_runtime.h>
#include <math.h>

typedef unsigned short u16;
typedef unsigned int u32;
typedef __attribute__((ext_vector_type(8))) short bf16x8;
typedef __attribute__((ext_vector_type(4))) float f32x4;

// ---------------- bf16 helpers (manual RNE; inputs are finite) ----------------
__device__ __forceinline__ u16 f2bf(float x) {
    u32 b = __builtin_bit_cast(u32, x);
    b += 0x7FFFu + ((b >> 16) & 1u);
    return (u16)(b >> 16);
}
__device__ __forceinline__ float bf2f(u16 u) {
    u32 b = ((u32)u) << 16;
    return __builtin_bit_cast(float, b);
}

// Swizzled tiled plane address, in 16-byte units.
// Plane layout: [row/128][c/64] tiles of 1024 units;
// unit-in-tile = (row&127)*8 + (slot ^ (row&7)), slot = (c&63)>>3.
__device__ __forceinline__ size_t sw_unit(int row, int c, int CC) {
    int slot = (c & 63) >> 3;
    return ((size_t)((row >> 7) * CC + (c >> 6)) << 10)
         + (size_t)((row & 127) << 3) + (size_t)(slot ^ (row & 7));
}

// ---------------------------------------------------------------------------
// prep: activations + weights -> swizzled bf16 HI planes (all single-plane:
// X_lo shown free R10/R11; Wfuse_lo dropped this round by the same budget).
// ---------------------------------------------------------------------------
__device__ void prep_x(const float* __restrict__ X, int C, int HW, int bl, int PT,
                       u16* __restrict__ dh) {
    __shared__ float Xt[64][65];
    const int t = threadIdx.x;
    const int pt = bl % PT, ct = bl / PT;
    const int p0 = pt * 64, c0 = ct * 64;
    const int b = p0 / HW, hw0 = p0 % HW;
    #pragma unroll
    for (int i = 0; i < 16; i++) {
        int r = (t >> 6) + i * 4;
        Xt[r][t & 63] = X[(size_t)(b * C + c0 + r) * HW + hw0 + (t & 63)];
    }
    __syncthreads();
    const int CC = C >> 6;
    #pragma unroll
    for (int it = 0; it < 2; it++) {
        int id = t + it * 256;
        int px = id >> 3, sl = id & 7;
        bf16x8 hv;
        #pragma unroll
        for (int j = 0; j < 8; j++)
            hv[j] = (short)f2bf(Xt[sl * 8 + j][px]);
        size_t unit = sw_unit(p0 + px, c0 + sl * 8, CC);
        *(bf16x8*)(dh + unit * 8) = hv;
    }
}

__device__ void prep_w(const float* __restrict__ W, int C, int bl,
                       u16* __restrict__ dh) {
    const int t = threadIdx.x;
    const int ot = bl & 3, cc = bl >> 2;
    const int o0 = ot * 64, c0 = cc * 64;
    const int CC = C >> 6;
    #pragma unroll
    for (int it = 0; it < 2; it++) {
        int id = t + it * 256;
        int ol = id >> 3, sl = id & 7;
        int o = o0 + ol, c = c0 + sl * 8;
        const float* wp = W + (size_t)o * C + c;
        float4 a = *(const float4*)wp;
        float4 b2 = *(const float4*)(wp + 4);
        float xs[8] = {a.x, a.y, a.z, a.w, b2.x, b2.y, b2.z, b2.w};
        bf16x8 hv;
        #pragma unroll
        for (int j = 0; j < 8; j++)
            hv[j] = (short)f2bf(xs[j]);
        size_t unit = sw_unit(o, c, CC);
        *(bf16x8*)(dh + unit * 8) = hv;
    }
}

// W plane offsets (u16 units) inside Whi
#define OFF_WQ 0
#define OFF_WK0 65536
#define OFF_WV0 163840
#define OFF_WK1 262144
#define OFF_WV1 458752
#define OFF_WFUSE 655360

__global__ __launch_bounds__(256) void prep_k(
    const float* __restrict__ query, const float* __restrict__ mem0, const float* __restrict__ mem1,
    const float* __restrict__ Wq, const float* __restrict__ Wk0, const float* __restrict__ Wv0,
    const float* __restrict__ Wk1, const float* __restrict__ Wv1, const float* __restrict__ Wfuse,
    u16* Xq_hi, u16* Xm0_hi, u16* Xm1_hi, u16* Whi)
{
    const int bx = blockIdx.x;
    if (bx < 512)      prep_x(query, 256, 4096, bx,       128, Xq_hi);
    else if (bx < 704) prep_x(mem0,  384, 1024, bx - 512,  32, Xm0_hi);
    else if (bx < 800) prep_x(mem1,  768,  256, bx - 704,   8, Xm1_hi);
    else {
        int r = bx - 800;
        if (r < 16)       prep_w(Wq,    256, r,       Whi + OFF_WQ);
        else if (r < 40)  prep_w(Wk0,   384, r - 16,  Whi + OFF_WK0);
        else if (r < 64)  prep_w(Wv0,   384, r - 40,  Whi + OFF_WV0);
        else if (r < 112) prep_w(Wk1,   768, r - 64,  Whi + OFF_WK1);
        else if (r < 160) prep_w(Wv1,   768, r - 112, Whi + OFF_WV1);
        else              prep_w(Wfuse, 512, r - 160, Whi + OFF_WFUSE);
    }
}

// ---------------------------------------------------------------------------
// 1-term bf16 MFMA GEMM core (proj): D = Ahi·Bhi (+bias).
// Block 128x128, 4 waves of 64x64 (4x4 16x16 D-tiles), KC=64, 2 LDS planes
// (32 KB), 2-phase pipelined staging (R8-proven). Y u16 pixel-major [row][256].
// ---------------------------------------------------------------------------
__device__ __forceinline__ void gemm_core(
    const u16* __restrict__ Ahi, const u16* __restrict__ Bhi,
    const float* __restrict__ bias, u16* __restrict__ Y,
    int CC, int am, int bn, u16* smem)
{
    const int t = threadIdx.x, lane = t & 63, w = t >> 6;
    const int wr = w >> 1, wc = w & 1;
    const int l15 = lane & 15;

    f32x4 acc[4][4];
    #pragma unroll
    for (int a = 0; a < 4; a++)
        #pragma unroll
        for (int b2 = 0; b2 < 4; b2++)
            acc[a][b2] = (f32x4){0.f, 0.f, 0.f, 0.f};

    bf16x8 stg[2][4];
    // ---- prologue: load chunk 0 ----
    {
        const size_t aoff = ((size_t)(am * CC)) << 13;
        const size_t boff = ((size_t)(bn * CC)) << 13;
        #pragma unroll
        for (int it = 0; it < 4; it++) {
            const size_t o = (size_t)(t + it * 256) * 8;
            stg[0][it] = *(const bf16x8*)(Ahi + aoff + o);
            stg[1][it] = *(const bf16x8*)(Bhi + boff + o);
        }
    }

    for (int ck = 0; ck < CC; ck++) {
        __syncthreads();   // prior chunk's LDS reads done
        #pragma unroll
        for (int p = 0; p < 2; p++)
            #pragma unroll
            for (int it = 0; it < 4; it++)
                *(bf16x8*)(smem + p * 8192 + (size_t)(t + it * 256) * 8) = stg[p][it];
        __syncthreads();   // chunk staged

        // ---- prefetch next chunk (clamped; last-iter re-read harmless) ----
        {
            const int cn = (ck + 1 < CC) ? ck + 1 : ck;
            const size_t aoff = ((size_t)(am * CC + cn)) << 13;
            const size_t boff = ((size_t)(bn * CC + cn)) << 13;
            #pragma unroll
            for (int it = 0; it < 4; it++) {
                const size_t o = (size_t)(t + it * 256) * 8;
                stg[0][it] = *(const bf16x8*)(Ahi + aoff + o);
                stg[1][it] = *(const bf16x8*)(Bhi + boff + o);
            }
        }

        // ---- compute: 2 k-steps of 32 ----
        #pragma unroll
        for (int kk = 0; kk < 2; kk++) {
            bf16x8 ah[4], bh[4];
            #pragma unroll
            for (int tr = 0; tr < 4; tr++) {
                int row = wr * 64 + tr * 16 + l15;
                int off = row * 64 + (((kk * 4 + (lane >> 4)) ^ (row & 7)) << 3);
                ah[tr] = *(const bf16x8*)(smem + off);
            }
            #pragma unroll
            for (int tc = 0; tc < 4; tc++) {
                int row = wc * 64 + tc * 16 + l15;
                int off = row * 64 + (((kk * 4 + (lane >> 4)) ^ (row & 7)) << 3);
                bh[tc] = *(const bf16x8*)(smem + 8192 + off);
            }
            #pragma unroll
            for (int tr = 0; tr < 4; tr++)
                #pragma unroll
                for (int tc = 0; tc < 4; tc++)
                    acc[tr][tc] = __builtin_amdgcn_mfma_f32_16x16x32_bf16(ah[tr], bh[tc], acc[tr][tc], 0, 0, 0);
        }
    }

    // ---- epilogue: D row = (lane>>4)*4+i, col = l15 (m89-verified) ----
    float bv[4];
    #pragma unroll
    for (int tc = 0; tc < 4; tc++)
        bv[tc] = bias[bn * 128 + wc * 64 + tc * 16 + l15];
    #pragma unroll
    for (int tr = 0; tr < 4; tr++) {
        #pragma unroll
        for (int i = 0; i < 4; i++) {
            int rp = am * 128 + wr * 64 + tr * 16 + ((lane >> 4) << 2) + i;
            u16* yr = Y + (size_t)rp * 256 + bn * 128 + wc * 64 + l15;
            #pragma unroll
            for (int tc = 0; tc < 4; tc++)
                yr[tc * 16] = f2bf(acc[tr][tc][i] + bv[tc]);
        }
    }
}

// proj: q / k0 / v0 / k1 / v1 in one 208-block dispatch (1-term bf16)
__global__ __launch_bounds__(256) void projmm_k(
    const u16* __restrict__ Xq_hi, const u16* __restrict__ Xm0_hi,
    const u16* __restrict__ Xm1_hi, const u16* __restrict__ Whi,
    const float* __restrict__ bq, const float* __restrict__ bk0, const float* __restrict__ bv0,
    const float* __restrict__ bk1, const float* __restrict__ bv1,
    u16* qT, u16* k0T, u16* v0T, u16* k1T, u16* v1T)
{
    __shared__ u16 smem[16384];   // 32 KB
    const int bx = blockIdx.x;
    if (bx < 128) {
        gemm_core(Xq_hi, Whi + OFF_WQ, bq, qT, 4, bx >> 1, bx & 1, smem);
    } else if (bx < 192) {
        const int r = bx - 128, am = r >> 2, bnn = r & 3;
        if (bnn < 2) gemm_core(Xm0_hi, Whi + OFF_WK0, bk0, k0T, 6, am, bnn, smem);
        else         gemm_core(Xm0_hi, Whi + OFF_WV0, bv0, v0T, 6, am, bnn - 2, smem);
    } else {
        const int r = bx - 192, am = r >> 2, bnn = r & 3;
        if (bnn < 2) gemm_core(Xm1_hi, Whi + OFF_WK1, bk1, k1T, 12, am, bnn, smem);
        else         gemm_core(Xm1_hi, Whi + OFF_WV1, bv1, v1T, 12, am, bnn - 2, smem);
    }
}

// ---------------------------------------------------------------------------
// fuse GEMM (1-term): out[o][p] = Whi_fuse[o]·fused[p] + bfuse.
// A-tile 64 rows (am 0..3), B-tile 128 px (bn 0..63) -> grid 256, LDS 24 KB.
// Waves: wr = 32-row half of A, wc = 64-px half of B; acc 2x4.
// A slab = half of a 128-row plane tile: units [(am&1)*512, +512).
// ---------------------------------------------------------------------------
__global__ __launch_bounds__(256) void fusemm_k(
    const u16* __restrict__ Whi, const u16* __restrict__ fhi,
    const float* __restrict__ bias, float* __restrict__ out)
{
    __shared__ u16 smem[12288];   // A 4096 u16 (8 KB) + B 8192 u16 (16 KB)
    const int t = threadIdx.x, lane = t & 63, w = t >> 6;
    const int wr = w >> 1, wc = w & 1;
    const int l15 = lane & 15;
    const int am = blockIdx.x & 3, bn = blockIdx.x >> 2;
    const u16* A = Whi + OFF_WFUSE;

    f32x4 acc[2][4];
    #pragma unroll
    for (int a = 0; a < 2; a++)
        #pragma unroll
        for (int b2 = 0; b2 < 4; b2++)
            acc[a][b2] = (f32x4){0.f, 0.f, 0.f, 0.f};

    bf16x8 stgA[2], stgB[4];
    // ---- prologue: load chunk 0 ----
    {
        const size_t aoff = (((size_t)(am >> 1) * 8) << 10) + (size_t)(am & 1) * 512;
        const size_t boff = ((size_t)(bn * 8)) << 10;
        #pragma unroll
        for (int it = 0; it < 2; it++)
            stgA[it] = *(const bf16x8*)(A + (aoff + t + it * 256) * 8);
        #pragma unroll
        for (int it = 0; it < 4; it++)
            stgB[it] = *(const bf16x8*)(fhi + (boff + t + it * 256) * 8);
    }

    for (int ck = 0; ck < 8; ck++) {
        __syncthreads();
        #pragma unroll
        for (int it = 0; it < 2; it++)
            *(bf16x8*)(smem + (size_t)(t + it * 256) * 8) = stgA[it];
        #pragma unroll
        for (int it = 0; it < 4; it++)
            *(bf16x8*)(smem + 4096 + (size_t)(t + it * 256) * 8) = stgB[it];
        __syncthreads();

        // ---- prefetch next chunk ----
        {
            const int cn = (ck + 1 < 8) ? ck + 1 : ck;
            const size_t aoff = (((size_t)(am >> 1) * 8 + cn) << 10) + (size_t)(am & 1) * 512;
            const size_t boff = ((size_t)(bn * 8 + cn)) << 10;
            #pragma unroll
            for (int it = 0; it < 2; it++)
                stgA[it] = *(const bf16x8*)(A + (aoff + t + it * 256) * 8);
            #pragma unroll
            for (int it = 0; it < 4; it++)
                stgB[it] = *(const bf16x8*)(fhi + (boff + t + it * 256) * 8);
        }

        #pragma unroll
        for (int kk = 0; kk < 2; kk++) {
            bf16x8 ah[2], bh[4];
            #pragma unroll
            for (int tr = 0; tr < 2; tr++) {
                int row = wr * 32 + tr * 16 + l15;
                int off = row * 64 + (((kk * 4 + (lane >> 4)) ^ (row & 7)) << 3);
                ah[tr] = *(const bf16x8*)(smem + off);
            }
            #pragma unroll
            for (int tc = 0; tc < 4; tc++) {
                int row = wc * 64 + tc * 16 + l15;
                int off = row * 64 + (((kk * 4 + (lane >> 4)) ^ (row & 7)) << 3);
                bh[tc] = *(const bf16x8*)(smem + 4096 + off);
            }
            #pragma unroll
            for (int tr = 0; tr < 2; tr++)
                #pragma unroll
                for (int tc = 0; tc < 4; tc++)
                    acc[tr][tc] = __builtin_amdgcn_mfma_f32_16x16x32_bf16(ah[tr], bh[tc], acc[tr][tc], 0, 0, 0);
        }
    }

    // ---- epilogue: D row = out-channel, col = pixel; out channel-major ----
    #pragma unroll
    for (int tr = 0; tr < 2; tr++) {
        #pragma unroll
        for (int i = 0; i < 4; i++) {
            const int o = am * 64 + wr * 32 + tr * 16 + ((lane >> 4) << 2) + i;
            const float bv = bias[o];
            #pragma unroll
            for (int tc = 0; tc < 4; tc++) {
                const int pcol = bn * 128 + wc * 64 + tc * 16 + l15;
                out[(size_t)((pcol >> 12) * 256 + o) * 4096 + (pcol & 4095)] = acc[tr][tc][i] + bv;
            }
        }
    }
}

// ---------------------------------------------------------------------------
// MFMA attention (R5/R8/R10-proven, unchanged). One wave per (b, head, 4x4
// q-tile); 8x8 candidate superset, mask to window+borders; S = Q·K^T, wave
// softmax, P->LDS, O = P·V with clamped scalar V-gather.
// ---------------------------------------------------------------------------
template<int SCALE>
__device__ __forceinline__ void attn_mfma(
    const u16* __restrict__ qT, const u16* __restrict__ kT,
    const u16* __restrict__ vT, u16* __restrict__ fhi,
    int b, int n, int ty, int tx, int lane, u16* s_lds)
{
    constexpr int HM = SCALE ? 16 : 32;
    const int qy0 = ty * 4, qx0 = tx * 4;
    const int ay0 = SCALE ? (qy0 >> 2) : (qy0 >> 1);
    const int ax0 = SCALE ? (qx0 >> 2) : (qx0 >> 1);
    const int l15 = lane & 15, kg = lane >> 4;

    const int pA = (b * 64 + qy0 + (l15 >> 2)) * 64 + qx0 + (l15 & 3);
    const bf16x8 qf = *(const bf16x8*)(qT + (size_t)pA * 256 + n * 32 + kg * 8);

    f32x4 s[4];
    #pragma unroll
    for (int t = 0; t < 4; t++) {
        const int cand = t * 16 + l15;
        const int wy = cand >> 3, wx = cand & 7;
        const int my = SCALE ? (ay0 + (wy - 2) * 2) : (ay0 - 3 + wy);
        const int mx = SCALE ? (ax0 + (wx - 2) * 2) : (ax0 - 3 + wx);
        const int myc = min(max(my, 0), HM - 1), mxc = min(max(mx, 0), HM - 1);
        const bf16x8 kf = *(const bf16x8*)(kT + (size_t)((b * HM + myc) * HM + mxc) * 256 + n * 32 + kg * 8);
        s[t] = __builtin_amdgcn_mfma_f32_16x16x32_bf16(qf, kf, (f32x4){0.f, 0.f, 0.f, 0.f}, 0, 0, 0);
    }

    const float scl = 0.17677669529663687f;
    float sv[4][4];
    #pragma unroll
    for (int t = 0; t < 4; t++) {
        const int cand = t * 16 + l15;
        const int wy = cand >> 3, wx = cand & 7;
        const int my = SCALE ? (ay0 + (wy - 2) * 2) : (ay0 - 3 + wy);
        const int mx = SCALE ? (ax0 + (wx - 2) * 2) : (ax0 - 3 + wx);
        const bool inb = (my >= 0) && (my < HM) && (mx >= 0) && (mx < HM);
        #pragma unroll
        for (int i = 0; i < 4; i++) {
            bool ok;
            if (SCALE) {
                ok = inb && (wy < 5) && (wx < 5);
            } else {
                const int r = kg * 4 + i;
                const int dy2 = (r >> 2) >> 1, dx2 = (r & 3) >> 1;
                ok = inb && ((u32)(wy - dy2) <= 6u) && ((u32)(wx - dx2) <= 6u);
            }
            sv[t][i] = ok ? s[t][i] * scl : -1e30f;
        }
    }

    float linv[4];
    #pragma unroll
    for (int i = 0; i < 4; i++) {
        float m = fmaxf(fmaxf(sv[0][i], sv[1][i]), fmaxf(sv[2][i], sv[3][i]));
        #pragma unroll
        for (int dd = 1; dd < 16; dd <<= 1) m = fmaxf(m, __shfl_xor(m, dd, 64));
        float l = 0.f;
        #pragma unroll
        for (int t = 0; t < 4; t++) { sv[t][i] = __expf(sv[t][i] - m); l += sv[t][i]; }
        #pragma unroll
        for (int dd = 1; dd < 16; dd <<= 1) l += __shfl_xor(l, dd, 64);
        linv[i] = 1.f / l;
    }

    #pragma unroll
    for (int t = 0; t < 4; t++)
        #pragma unroll
        for (int i = 0; i < 4; i++)
            s_lds[(kg * 4 + i) * 68 + t * 16 + l15] = f2bf(sv[t][i]);
    __syncthreads();

    f32x4 o[2] = {(f32x4){0.f,0.f,0.f,0.f}, (f32x4){0.f,0.f,0.f,0.f}};
    #pragma unroll
    for (int h = 0; h < 2; h++) {
        const bf16x8 pa = *(const bf16x8*)(s_lds + l15 * 68 + h * 32 + kg * 8);
        #pragma unroll
        for (int c = 0; c < 2; c++) {
            bf16x8 vf;
            #pragma unroll
            for (int j = 0; j < 8; j++) {
                const int cand = h * 32 + kg * 8 + j;
                const int wy = cand >> 3, wx = cand & 7;
                int my = SCALE ? (ay0 + (wy - 2) * 2) : (ay0 - 3 + wy);
                int mx = SCALE ? (ax0 + (wx - 2) * 2) : (ax0 - 3 + wx);
                my = min(max(my, 0), HM - 1); mx = min(max(mx, 0), HM - 1);
                vf[j] = (short)vT[(size_t)((b * HM + my) * HM + mx) * 256 + n * 32 + c * 16 + l15];
            }
            o[c] = __builtin_amdgcn_mfma_f32_16x16x32_bf16(pa, vf, o[c], 0, 0, 0);
        }
    }

    #pragma unroll
    for (int c = 0; c < 2; c++) {
        #pragma unroll
        for (int i = 0; i < 4; i++) {
            const int r = kg * 4 + i;
            const int p = (b * 64 + qy0 + (r >> 2)) * 64 + qx0 + (r & 3);
            const int ch = (SCALE ? 256 : 0) + n * 32 + c * 16 + l15;
            fhi[sw_unit(p, ch, 8) * 8 + (ch & 7)] = f2bf(o[c][i] * linv[i]);
        }
    }
}

__global__ __launch_bounds__(256) void attn_k(
    const u16* __restrict__ qT,
    const u16* __restrict__ k0T, const u16* __restrict__ v0T,
    const u16* __restrict__ k1T, const u16* __restrict__ v1T,
    u16* __restrict__ fhi)
{
    __shared__ u16 s_lds[4][16 * 68];
    const int t = threadIdx.x, w = t >> 6, lane = t & 63;
    const int bx = blockIdx.x;
    const int sc = bx >> 10;
    const int tile = (bx & 1023) * 4 + w;
    const int b = tile >> 11, n = (tile >> 8) & 7;
    const int ty = (tile >> 4) & 15, tx = tile & 15;
    if (sc == 0) attn_mfma<0>(qT, k0T, v0T, fhi, b, n, ty, tx, lane, s_lds[w]);
    else         attn_mfma<1>(qT, k1T, v1T, fhi, b, n, ty, tx, lane, s_lds[w]);
}

// ---------------------------------------------------------------------------
extern "C" void kernel_launch(void* const* d_in, const int* in_sizes, int n_in,
                              void* d_out, int out_size, void* d_ws, size_t ws_size,
                              hipStream_t stream)
{
    const float* query = (const float*)d_in[0];
    const float* mem0  = (const float*)d_in[1];
    const float* mem1  = (const float*)d_in[2];
    const float* Wq    = (const float*)d_in[3];  const float* bq    = (const float*)d_in[4];
    const float* Wk0   = (const float*)d_in[5];  const float* bk0   = (const float*)d_in[6];
    const float* Wv0   = (const float*)d_in[7];  const float* bv0   = (const float*)d_in[8];
    const float* Wk1   = (const float*)d_in[9];  const float* bk1   = (const float*)d_in[10];
    const float* Wv1   = (const float*)d_in[11]; const float* bv1   = (const float*)d_in[12];
    const float* Wfuse = (const float*)d_in[13]; const float* bfuse = (const float*)d_in[14];
    float* out = (float*)d_out;

    char* ws = (char*)d_ws;
    u16* qT       = (u16*)(ws + 0);            // 4 MB (bf16 pixel-major)
    u16* k0T      = (u16*)(ws + 8388608);      // 1 MB
    u16* v0T      = (u16*)(ws + 10485760);     // 1 MB
    u16* k1T      = (u16*)(ws + 12582912);     // 256 KB
    u16* v1T      = (u16*)(ws + 13107200);     // 256 KB
    u16* Whi      = (u16*)(ws + 13631488);     // 1.5 MB
    u16* Xm0_hi   = (u16*)(ws + 16777216);     // 1.5 MB
    u16* Xm1_hi   = (u16*)(ws + 19922944);     // 768 KB
    u16* Xq_hi    = (u16*)(ws + 21495808);     // 4 MB
    u16* fhi      = Xq_hi;                     // fused plane (8 MB: Xq_hi + next 4 MB)

    prep_k<<<dim3(992), 256, 0, stream>>>(
        query, mem0, mem1, Wq, Wk0, Wv0, Wk1, Wv1, Wfuse,
        Xq_hi, Xm0_hi, Xm1_hi, Whi);

    projmm_k<<<dim3(208), 256, 0, stream>>>(
        Xq_hi, Xm0_hi, Xm1_hi, Whi,
        bq, bk0, bv0, bk1, bv1, qT, k0T, v0T, k1T, v1T);

    attn_k<<<dim3(2048), 256, 0, stream>>>(qT, k0T, v0T, k1T, v1T, fhi);

    fusemm_k<<<dim3(256), 256, 0, stream>>>(Whi, fhi, bfuse, out);
}

// Round 14
// 48.539 us; speedup vs baseline: 1.5289x; 1.0345x over previous
//
#include <hip/hip_runtime.h>
#include <math.h>

typedef unsigned short u16;
typedef unsigned int u32;
typedef __attribute__((ext_vector_type(8))) short bf16x8;
typedef __attribute__((ext_vector_type(4))) float f32x4;

// ---------------- bf16 helpers (manual RNE; inputs are finite) ----------------
__device__ __forceinline__ u16 f2bf(float x) {
    u32 b = __builtin_bit_cast(u32, x);
    b += 0x7FFFu + ((b >> 16) & 1u);
    return (u16)(b >> 16);
}
__device__ __forceinline__ float bf2f(u16 u) {
    u32 b = ((u32)u) << 16;
    return __builtin_bit_cast(float, b);
}

// Swizzled tiled plane address, in 16-byte units.
// Plane layout: [row/128][c/64] tiles of 1024 units;
// unit-in-tile = (row&127)*8 + (slot ^ (row&7)), slot = (c&63)>>3.
__device__ __forceinline__ size_t sw_unit(int row, int c, int CC) {
    int slot = (c & 63) >> 3;
    return ((size_t)((row >> 7) * CC + (c >> 6)) << 10)
         + (size_t)((row & 127) << 3) + (size_t)(slot ^ (row & 7));
}

// ---------------------------------------------------------------------------
// prep: activations + weights -> swizzled bf16 HI planes (R11/R12-proven).
// ---------------------------------------------------------------------------
__device__ void prep_x(const float* __restrict__ X, int C, int HW, int bl, int PT,
                       u16* __restrict__ dh) {
    __shared__ float Xt[64][65];
    const int t = threadIdx.x;
    const int pt = bl % PT, ct = bl / PT;
    const int p0 = pt * 64, c0 = ct * 64;
    const int b = p0 / HW, hw0 = p0 % HW;
    #pragma unroll
    for (int i = 0; i < 16; i++) {
        int r = (t >> 6) + i * 4;
        Xt[r][t & 63] = X[(size_t)(b * C + c0 + r) * HW + hw0 + (t & 63)];
    }
    __syncthreads();
    const int CC = C >> 6;
    #pragma unroll
    for (int it = 0; it < 2; it++) {
        int id = t + it * 256;
        int px = id >> 3, sl = id & 7;
        bf16x8 hv;
        #pragma unroll
        for (int j = 0; j < 8; j++)
            hv[j] = (short)f2bf(Xt[sl * 8 + j][px]);
        size_t unit = sw_unit(p0 + px, c0 + sl * 8, CC);
        *(bf16x8*)(dh + unit * 8) = hv;
    }
}

__device__ void prep_w(const float* __restrict__ W, int C, int bl,
                       u16* __restrict__ dh) {
    const int t = threadIdx.x;
    const int ot = bl & 3, cc = bl >> 2;
    const int o0 = ot * 64, c0 = cc * 64;
    const int CC = C >> 6;
    #pragma unroll
    for (int it = 0; it < 2; it++) {
        int id = t + it * 256;
        int ol = id >> 3, sl = id & 7;
        int o = o0 + ol, c = c0 + sl * 8;
        const float* wp = W + (size_t)o * C + c;
        float4 a = *(const float4*)wp;
        float4 b2 = *(const float4*)(wp + 4);
        float xs[8] = {a.x, a.y, a.z, a.w, b2.x, b2.y, b2.z, b2.w};
        bf16x8 hv;
        #pragma unroll
        for (int j = 0; j < 8; j++)
            hv[j] = (short)f2bf(xs[j]);
        size_t unit = sw_unit(o, c, CC);
        *(bf16x8*)(dh + unit * 8) = hv;
    }
}

// W plane offsets (u16 units) inside Whi
#define OFF_WQ 0
#define OFF_WK0 65536
#define OFF_WV0 163840
#define OFF_WK1 262144
#define OFF_WV1 458752
#define OFF_WFUSE 655360

__global__ __launch_bounds__(256) void prep_k(
    const float* __restrict__ query, const float* __restrict__ mem0, const float* __restrict__ mem1,
    const float* __restrict__ Wq, const float* __restrict__ Wk0, const float* __restrict__ Wv0,
    const float* __restrict__ Wk1, const float* __restrict__ Wv1, const float* __restrict__ Wfuse,
    u16* Xq_hi, u16* Xm0_hi, u16* Xm1_hi, u16* Whi)
{
    const int bx = blockIdx.x;
    if (bx < 512)      prep_x(query, 256, 4096, bx,       128, Xq_hi);
    else if (bx < 704) prep_x(mem0,  384, 1024, bx - 512,  32, Xm0_hi);
    else if (bx < 800) prep_x(mem1,  768,  256, bx - 704,   8, Xm1_hi);
    else {
        int r = bx - 800;
        if (r < 16)       prep_w(Wq,    256, r,       Whi + OFF_WQ);
        else if (r < 40)  prep_w(Wk0,   384, r - 16,  Whi + OFF_WK0);
        else if (r < 64)  prep_w(Wv0,   384, r - 40,  Whi + OFF_WV0);
        else if (r < 112) prep_w(Wk1,   768, r - 64,  Whi + OFF_WK1);
        else if (r < 160) prep_w(Wv1,   768, r - 112, Whi + OFF_WV1);
        else              prep_w(Wfuse, 512, r - 160, Whi + OFF_WFUSE);
    }
}

// ---------------------------------------------------------------------------
// 1-term bf16 MFMA GEMM core (proj): D = Ahi·Bhi (+bias). (R12-proven.)
// ---------------------------------------------------------------------------
__device__ __forceinline__ void gemm_core(
    const u16* __restrict__ Ahi, const u16* __restrict__ Bhi,
    const float* __restrict__ bias, u16* __restrict__ Y,
    int CC, int am, int bn, u16* smem)
{
    const int t = threadIdx.x, lane = t & 63, w = t >> 6;
    const int wr = w >> 1, wc = w & 1;
    const int l15 = lane & 15;

    f32x4 acc[4][4];
    #pragma unroll
    for (int a = 0; a < 4; a++)
        #pragma unroll
        for (int b2 = 0; b2 < 4; b2++)
            acc[a][b2] = (f32x4){0.f, 0.f, 0.f, 0.f};

    bf16x8 stg[2][4];
    {
        const size_t aoff = ((size_t)(am * CC)) << 13;
        const size_t boff = ((size_t)(bn * CC)) << 13;
        #pragma unroll
        for (int it = 0; it < 4; it++) {
            const size_t o = (size_t)(t + it * 256) * 8;
            stg[0][it] = *(const bf16x8*)(Ahi + aoff + o);
            stg[1][it] = *(const bf16x8*)(Bhi + boff + o);
        }
    }

    for (int ck = 0; ck < CC; ck++) {
        __syncthreads();
        #pragma unroll
        for (int p = 0; p < 2; p++)
            #pragma unroll
            for (int it = 0; it < 4; it++)
                *(bf16x8*)(smem + p * 8192 + (size_t)(t + it * 256) * 8) = stg[p][it];
        __syncthreads();

        {
            const int cn = (ck + 1 < CC) ? ck + 1 : ck;
            const size_t aoff = ((size_t)(am * CC + cn)) << 13;
            const size_t boff = ((size_t)(bn * CC + cn)) << 13;
            #pragma unroll
            for (int it = 0; it < 4; it++) {
                const size_t o = (size_t)(t + it * 256) * 8;
                stg[0][it] = *(const bf16x8*)(Ahi + aoff + o);
                stg[1][it] = *(const bf16x8*)(Bhi + boff + o);
            }
        }

        #pragma unroll
        for (int kk = 0; kk < 2; kk++) {
            bf16x8 ah[4], bh[4];
            #pragma unroll
            for (int tr = 0; tr < 4; tr++) {
                int row = wr * 64 + tr * 16 + l15;
                int off = row * 64 + (((kk * 4 + (lane >> 4)) ^ (row & 7)) << 3);
                ah[tr] = *(const bf16x8*)(smem + off);
            }
            #pragma unroll
            for (int tc = 0; tc < 4; tc++) {
                int row = wc * 64 + tc * 16 + l15;
                int off = row * 64 + (((kk * 4 + (lane >> 4)) ^ (row & 7)) << 3);
                bh[tc] = *(const bf16x8*)(smem + 8192 + off);
            }
            #pragma unroll
            for (int tr = 0; tr < 4; tr++)
                #pragma unroll
                for (int tc = 0; tc < 4; tc++)
                    acc[tr][tc] = __builtin_amdgcn_mfma_f32_16x16x32_bf16(ah[tr], bh[tc], acc[tr][tc], 0, 0, 0);
        }
    }

    float bv[4];
    #pragma unroll
    for (int tc = 0; tc < 4; tc++)
        bv[tc] = bias[bn * 128 + wc * 64 + tc * 16 + l15];
    #pragma unroll
    for (int tr = 0; tr < 4; tr++) {
        #pragma unroll
        for (int i = 0; i < 4; i++) {
            int rp = am * 128 + wr * 64 + tr * 16 + ((lane >> 4) << 2) + i;
            u16* yr = Y + (size_t)rp * 256 + bn * 128 + wc * 64 + l15;
            #pragma unroll
            for (int tc = 0; tc < 4; tc++)
                yr[tc * 16] = f2bf(acc[tr][tc][i] + bv[tc]);
        }
    }
}

// proj: q / k0 / v0 / k1 / v1 in one 208-block dispatch (1-term bf16)
__global__ __launch_bounds__(256) void projmm_k(
    const u16* __restrict__ Xq_hi, const u16* __restrict__ Xm0_hi,
    const u16* __restrict__ Xm1_hi, const u16* __restrict__ Whi,
    const float* __restrict__ bq, const float* __restrict__ bk0, const float* __restrict__ bv0,
    const float* __restrict__ bk1, const float* __restrict__ bv1,
    u16* qT, u16* k0T, u16* v0T, u16* k1T, u16* v1T)
{
    __shared__ u16 smem[16384];   // 32 KB
    const int bx = blockIdx.x;
    if (bx < 128) {
        gemm_core(Xq_hi, Whi + OFF_WQ, bq, qT, 4, bx >> 1, bx & 1, smem);
    } else if (bx < 192) {
        const int r = bx - 128, am = r >> 2, bnn = r & 3;
        if (bnn < 2) gemm_core(Xm0_hi, Whi + OFF_WK0, bk0, k0T, 6, am, bnn, smem);
        else         gemm_core(Xm0_hi, Whi + OFF_WV0, bv0, v0T, 6, am, bnn - 2, smem);
    } else {
        const int r = bx - 192, am = r >> 2, bnn = r & 3;
        if (bnn < 2) gemm_core(Xm1_hi, Whi + OFF_WK1, bk1, k1T, 12, am, bnn, smem);
        else         gemm_core(Xm1_hi, Whi + OFF_WV1, bv1, v1T, 12, am, bnn - 2, smem);
    }
}

// ---------------------------------------------------------------------------
// fuse GEMM (1-term, R12-proven): out[o][p] = Whi_fuse[o]·fused[p] + bfuse.
// ---------------------------------------------------------------------------
__global__ __launch_bounds__(256) void fusemm_k(
    const u16* __restrict__ Whi, const u16* __restrict__ fhi,
    const float* __restrict__ bias, float* __restrict__ out)
{
    __shared__ u16 smem[12288];
    const int t = threadIdx.x, lane = t & 63, w = t >> 6;
    const int wr = w >> 1, wc = w & 1;
    const int l15 = lane & 15;
    const int am = blockIdx.x & 3, bn = blockIdx.x >> 2;
    const u16* A = Whi + OFF_WFUSE;

    f32x4 acc[2][4];
    #pragma unroll
    for (int a = 0; a < 2; a++)
        #pragma unroll
        for (int b2 = 0; b2 < 4; b2++)
            acc[a][b2] = (f32x4){0.f, 0.f, 0.f, 0.f};

    bf16x8 stgA[2], stgB[4];
    {
        const size_t aoff = (((size_t)(am >> 1) * 8) << 10) + (size_t)(am & 1) * 512;
        const size_t boff = ((size_t)(bn * 8)) << 10;
        #pragma unroll
        for (int it = 0; it < 2; it++)
            stgA[it] = *(const bf16x8*)(A + (aoff + t + it * 256) * 8);
        #pragma unroll
        for (int it = 0; it < 4; it++)
            stgB[it] = *(const bf16x8*)(fhi + (boff + t + it * 256) * 8);
    }

    for (int ck = 0; ck < 8; ck++) {
        __syncthreads();
        #pragma unroll
        for (int it = 0; it < 2; it++)
            *(bf16x8*)(smem + (size_t)(t + it * 256) * 8) = stgA[it];
        #pragma unroll
        for (int it = 0; it < 4; it++)
            *(bf16x8*)(smem + 4096 + (size_t)(t + it * 256) * 8) = stgB[it];
        __syncthreads();

        {
            const int cn = (ck + 1 < 8) ? ck + 1 : ck;
            const size_t aoff = (((size_t)(am >> 1) * 8 + cn) << 10) + (size_t)(am & 1) * 512;
            const size_t boff = ((size_t)(bn * 8 + cn)) << 10;
            #pragma unroll
            for (int it = 0; it < 2; it++)
                stgA[it] = *(const bf16x8*)(A + (aoff + t + it * 256) * 8);
            #pragma unroll
            for (int it = 0; it < 4; it++)
                stgB[it] = *(const bf16x8*)(fhi + (boff + t + it * 256) * 8);
        }

        #pragma unroll
        for (int kk = 0; kk < 2; kk++) {
            bf16x8 ah[2], bh[4];
            #pragma unroll
            for (int tr = 0; tr < 2; tr++) {
                int row = wr * 32 + tr * 16 + l15;
                int off = row * 64 + (((kk * 4 + (lane >> 4)) ^ (row & 7)) << 3);
                ah[tr] = *(const bf16x8*)(smem + off);
            }
            #pragma unroll
            for (int tc = 0; tc < 4; tc++) {
                int row = wc * 64 + tc * 16 + l15;
                int off = row * 64 + (((kk * 4 + (lane >> 4)) ^ (row & 7)) << 3);
                bh[tc] = *(const bf16x8*)(smem + 4096 + off);
            }
            #pragma unroll
            for (int tr = 0; tr < 2; tr++)
                #pragma unroll
                for (int tc = 0; tc < 4; tc++)
                    acc[tr][tc] = __builtin_amdgcn_mfma_f32_16x16x32_bf16(ah[tr], bh[tc], acc[tr][tc], 0, 0, 0);
        }
    }

    #pragma unroll
    for (int tr = 0; tr < 2; tr++) {
        #pragma unroll
        for (int i = 0; i < 4; i++) {
            const int o = am * 64 + wr * 32 + tr * 16 + ((lane >> 4) << 2) + i;
            const float bv = bias[o];
            #pragma unroll
            for (int tc = 0; tc < 4; tc++) {
                const int pcol = bn * 128 + wc * 64 + tc * 16 + l15;
                out[(size_t)((pcol >> 12) * 256 + o) * 4096 + (pcol & 4095)] = acc[tr][tc][i] + bv;
            }
        }
    }
}

// ---------------------------------------------------------------------------
// MFMA attention. One wave per (b, head, 4x4 q-tile), NO block barrier
// (each wave uses its private LDS slice; intra-wave ds ordering via lgkmcnt).
// SCALE=0: 8x8 64-cand frame (4 QK + 4 PV MFMAs) — unchanged R5 math.
// SCALE=1: 5x6 30-cand frame in 2 tiles (2 QK + 2 PV MFMAs, 16 V-loads) —
//          covers the full 5x5 window; dropped slots were always masked.
// ---------------------------------------------------------------------------
template<int SCALE>
__device__ __forceinline__ void attn_mfma(
    const u16* __restrict__ qT, const u16* __restrict__ kT,
    const u16* __restrict__ vT, u16* __restrict__ fhi,
    int b, int n, int ty, int tx, int lane, u16* s_lds)
{
    constexpr int HM = SCALE ? 16 : 32;
    constexpr int NT = SCALE ? 2 : 4;      // 16-cand tiles
    const int qy0 = ty * 4, qx0 = tx * 4;
    const int ay0 = SCALE ? (qy0 >> 2) : (qy0 >> 1);
    const int ax0 = SCALE ? (qx0 >> 2) : (qx0 >> 1);
    const int l15 = lane & 15, kg = lane >> 4;

    const int pA = (b * 64 + qy0 + (l15 >> 2)) * 64 + qx0 + (l15 & 3);
    const bf16x8 qf = *(const bf16x8*)(qT + (size_t)pA * 256 + n * 32 + kg * 8);

    f32x4 s[NT];
    #pragma unroll
    for (int t = 0; t < NT; t++) {
        const int cand = t * 16 + l15;
        const int wy = SCALE ? (cand / 6) : (cand >> 3);
        const int wx = SCALE ? (cand % 6) : (cand & 7);
        const int my = SCALE ? (ay0 + (wy - 2) * 2) : (ay0 - 3 + wy);
        const int mx = SCALE ? (ax0 + (wx - 2) * 2) : (ax0 - 3 + wx);
        const int myc = min(max(my, 0), HM - 1), mxc = min(max(mx, 0), HM - 1);
        const bf16x8 kf = *(const bf16x8*)(kT + (size_t)((b * HM + myc) * HM + mxc) * 256 + n * 32 + kg * 8);
        s[t] = __builtin_amdgcn_mfma_f32_16x16x32_bf16(qf, kf, (f32x4){0.f, 0.f, 0.f, 0.f}, 0, 0, 0);
    }

    const float scl = 0.17677669529663687f;
    float sv[NT][4];
    #pragma unroll
    for (int t = 0; t < NT; t++) {
        const int cand = t * 16 + l15;
        const int wy = SCALE ? (cand / 6) : (cand >> 3);
        const int wx = SCALE ? (cand % 6) : (cand & 7);
        const int my = SCALE ? (ay0 + (wy - 2) * 2) : (ay0 - 3 + wy);
        const int mx = SCALE ? (ax0 + (wx - 2) * 2) : (ax0 - 3 + wx);
        const bool inb = (my >= 0) && (my < HM) && (mx >= 0) && (mx < HM);
        #pragma unroll
        for (int i = 0; i < 4; i++) {
            bool ok;
            if (SCALE) {
                ok = inb && (wy < 5) && (wx < 5);
            } else {
                const int r = kg * 4 + i;
                const int dy2 = (r >> 2) >> 1, dx2 = (r & 3) >> 1;
                ok = inb && ((u32)(wy - dy2) <= 6u) && ((u32)(wx - dx2) <= 6u);
            }
            sv[t][i] = ok ? s[t][i] * scl : -1e30f;
        }
    }

    float linv[4];
    #pragma unroll
    for (int i = 0; i < 4; i++) {
        float m = sv[0][i];
        #pragma unroll
        for (int t = 1; t < NT; t++) m = fmaxf(m, sv[t][i]);
        #pragma unroll
        for (int dd = 1; dd < 16; dd <<= 1) m = fmaxf(m, __shfl_xor(m, dd, 64));
        float l = 0.f;
        #pragma unroll
        for (int t = 0; t < NT; t++) { sv[t][i] = __expf(sv[t][i] - m); l += sv[t][i]; }
        #pragma unroll
        for (int dd = 1; dd < 16; dd <<= 1) l += __shfl_xor(l, dd, 64);
        linv[i] = 1.f / l;
    }

    // P -> private LDS slice (no block barrier: intra-wave lgkmcnt ordering)
    #pragma unroll
    for (int t = 0; t < NT; t++)
        #pragma unroll
        for (int i = 0; i < 4; i++)
            s_lds[(kg * 4 + i) * 68 + t * 16 + l15] = f2bf(sv[t][i]);

    f32x4 o[2] = {(f32x4){0.f,0.f,0.f,0.f}, (f32x4){0.f,0.f,0.f,0.f}};
    #pragma unroll
    for (int h = 0; h < NT / 2; h++) {
        const bf16x8 pa = *(const bf16x8*)(s_lds + l15 * 68 + h * 32 + kg * 8);
        #pragma unroll
        for (int c = 0; c < 2; c++) {
            bf16x8 vf;
            #pragma unroll
            for (int j = 0; j < 8; j++) {
                const int cand = h * 32 + kg * 8 + j;
                const int wy = SCALE ? (cand / 6) : (cand >> 3);
                const int wx = SCALE ? (cand % 6) : (cand & 7);
                int my = SCALE ? (ay0 + (wy - 2) * 2) : (ay0 - 3 + wy);
                int mx = SCALE ? (ax0 + (wx - 2) * 2) : (ax0 - 3 + wx);
                my = min(max(my, 0), HM - 1); mx = min(max(mx, 0), HM - 1);
                vf[j] = (short)vT[(size_t)((b * HM + my) * HM + mx) * 256 + n * 32 + c * 16 + l15];
            }
            o[c] = __builtin_amdgcn_mfma_f32_16x16x32_bf16(pa, vf, o[c], 0, 0, 0);
        }
    }

    #pragma unroll
    for (int c = 0; c < 2; c++) {
        #pragma unroll
        for (int i = 0; i < 4; i++) {
            const int r = kg * 4 + i;
            const int p = (b * 64 + qy0 + (r >> 2)) * 64 + qx0 + (r & 3);
            const int ch = (SCALE ? 256 : 0) + n * 32 + c * 16 + l15;
            fhi[sw_unit(p, ch, 8) * 8 + (ch & 7)] = f2bf(o[c][i] * linv[i]);
        }
    }
}

__global__ __launch_bounds__(256) void attn_k(
    const u16* __restrict__ qT,
    const u16* __restrict__ k0T, const u16* __restrict__ v0T,
    const u16* __restrict__ k1T, const u16* __restrict__ v1T,
    u16* __restrict__ fhi)
{
    __shared__ u16 s_lds[4][16 * 68];
    const int t = threadIdx.x, w = t >> 6, lane = t & 63;
    const int bx = blockIdx.x;
    const int sc = bx >> 10;
    const int tile = (bx & 1023) * 4 + w;
    const int b = tile >> 11, n = (tile >> 8) & 7;
    const int ty = (tile >> 4) & 15, tx = tile & 15;
    if (sc == 0) attn_mfma<0>(qT, k0T, v0T, fhi, b, n, ty, tx, lane, s_lds[w]);
    else         attn_mfma<1>(qT, k1T, v1T, fhi, b, n, ty, tx, lane, s_lds[w]);
}

// ---------------------------------------------------------------------------
extern "C" void kernel_launch(void* const* d_in, const int* in_sizes, int n_in,
                              void* d_out, int out_size, void* d_ws, size_t ws_size,
                              hipStream_t stream)
{
    const float* query = (const float*)d_in[0];
    const float* mem0  = (const float*)d_in[1];
    const float* mem1  = (const float*)d_in[2];
    const float* Wq    = (const float*)d_in[3];  const float* bq    = (const float*)d_in[4];
    const float* Wk0   = (const float*)d_in[5];  const float* bk0   = (const float*)d_in[6];
    const float* Wv0   = (const float*)d_in[7];  const float* bv0   = (const float*)d_in[8];
    const float* Wk1   = (const float*)d_in[9];  const float* bk1   = (const float*)d_in[10];
    const float* Wv1   = (const float*)d_in[11]; const float* bv1   = (const float*)d_in[12];
    const float* Wfuse = (const float*)d_in[13]; const float* bfuse = (const float*)d_in[14];
    float* out = (float*)d_out;

    char* ws = (char*)d_ws;
    u16* qT       = (u16*)(ws + 0);            // 4 MB (bf16 pixel-major)
    u16* k0T      = (u16*)(ws + 8388608);      // 1 MB
    u16* v0T      = (u16*)(ws + 10485760);     // 1 MB
    u16* k1T      = (u16*)(ws + 12582912);     // 256 KB
    u16* v1T      = (u16*)(ws + 13107200);     // 256 KB
    u16* Whi      = (u16*)(ws + 13631488);     // 1.5 MB
    u16* Xm0_hi   = (u16*)(ws + 16777216);     // 1.5 MB
    u16* Xm1_hi   = (u16*)(ws + 19922944);     // 768 KB
    u16* Xq_hi    = (u16*)(ws + 21495808);     // 4 MB
    u16* fhi      = Xq_hi;                     // fused plane (8 MB: Xq_hi + next 4 MB)

    prep_k<<<dim3(992), 256, 0, stream>>>(
        query, mem0, mem1, Wq, Wk0, Wv0, Wk1, Wv1, Wfuse,
        Xq_hi, Xm0_hi, Xm1_hi, Whi);

    projmm_k<<<dim3(208), 256, 0, stream>>>(
        Xq_hi, Xm0_hi, Xm1_hi, Whi,
        bq, bk0, bv0, bk1, bv1, qT, k0T, v0T, k1T, v1T);

    attn_k<<<dim3(2048), 256, 0, stream>>>(qT, k0T, v0T, k1T, v1T, fhi);

    fusemm_k<<<dim3(256), 256, 0, stream>>>(Whi, fhi, bfuse, out);
}

// Round 15
// 45.709 us; speedup vs baseline: 1.6235x; 1.0619x over previous
//
#include <hip/hip_runtime.h>
#include <math.h>

typedef unsigned short u16;
typedef unsigned int u32;
typedef __attribute__((ext_vector_type(8))) short bf16x8;
typedef __attribute__((ext_vector_type(4))) float f32x4;

// ---------------- bf16 helpers (manual RNE; inputs are finite) ----------------
__device__ __forceinline__ u16 f2bf(float x) {
    u32 b = __builtin_bit_cast(u32, x);
    b += 0x7FFFu + ((b >> 16) & 1u);
    return (u16)(b >> 16);
}
__device__ __forceinline__ float bf2f(u16 u) {
    u32 b = ((u32)u) << 16;
    return __builtin_bit_cast(float, b);
}

// Swizzled tiled plane address, in 16-byte units.
// Plane layout: [row/128][c/64] tiles of 1024 units;
// unit-in-tile = (row&127)*8 + (slot ^ (row&7)), slot = (c&63)>>3.
__device__ __forceinline__ size_t sw_unit(int row, int c, int CC) {
    int slot = (c & 63) >> 3;
    return ((size_t)((row >> 7) * CC + (c >> 6)) << 10)
         + (size_t)((row & 127) << 3) + (size_t)(slot ^ (row & 7));
}

// ---------------------------------------------------------------------------
// prep: activations + weights -> swizzled bf16 HI planes (R11/R12-proven).
// ---------------------------------------------------------------------------
__device__ void prep_x(const float* __restrict__ X, int C, int HW, int bl, int PT,
                       u16* __restrict__ dh) {
    __shared__ float Xt[64][65];
    const int t = threadIdx.x;
    const int pt = bl % PT, ct = bl / PT;
    const int p0 = pt * 64, c0 = ct * 64;
    const int b = p0 / HW, hw0 = p0 % HW;
    #pragma unroll
    for (int i = 0; i < 16; i++) {
        int r = (t >> 6) + i * 4;
        Xt[r][t & 63] = X[(size_t)(b * C + c0 + r) * HW + hw0 + (t & 63)];
    }
    __syncthreads();
    const int CC = C >> 6;
    #pragma unroll
    for (int it = 0; it < 2; it++) {
        int id = t + it * 256;
        int px = id >> 3, sl = id & 7;
        bf16x8 hv;
        #pragma unroll
        for (int j = 0; j < 8; j++)
            hv[j] = (short)f2bf(Xt[sl * 8 + j][px]);
        size_t unit = sw_unit(p0 + px, c0 + sl * 8, CC);
        *(bf16x8*)(dh + unit * 8) = hv;
    }
}

__device__ void prep_w(const float* __restrict__ W, int C, int bl,
                       u16* __restrict__ dh) {
    const int t = threadIdx.x;
    const int ot = bl & 3, cc = bl >> 2;
    const int o0 = ot * 64, c0 = cc * 64;
    const int CC = C >> 6;
    #pragma unroll
    for (int it = 0; it < 2; it++) {
        int id = t + it * 256;
        int ol = id >> 3, sl = id & 7;
        int o = o0 + ol, c = c0 + sl * 8;
        const float* wp = W + (size_t)o * C + c;
        float4 a = *(const float4*)wp;
        float4 b2 = *(const float4*)(wp + 4);
        float xs[8] = {a.x, a.y, a.z, a.w, b2.x, b2.y, b2.z, b2.w};
        bf16x8 hv;
        #pragma unroll
        for (int j = 0; j < 8; j++)
            hv[j] = (short)f2bf(xs[j]);
        size_t unit = sw_unit(o, c, CC);
        *(bf16x8*)(dh + unit * 8) = hv;
    }
}

// W plane offsets (u16 units) inside Whi
#define OFF_WQ 0
#define OFF_WK0 65536
#define OFF_WV0 163840
#define OFF_WK1 262144
#define OFF_WV1 458752
#define OFF_WFUSE 655360

__global__ __launch_bounds__(256) void prep_k(
    const float* __restrict__ query, const float* __restrict__ mem0, const float* __restrict__ mem1,
    const float* __restrict__ Wq, const float* __restrict__ Wk0, const float* __restrict__ Wv0,
    const float* __restrict__ Wk1, const float* __restrict__ Wv1, const float* __restrict__ Wfuse,
    u16* Xq_hi, u16* Xm0_hi, u16* Xm1_hi, u16* Whi)
{
    const int bx = blockIdx.x;
    if (bx < 512)      prep_x(query, 256, 4096, bx,       128, Xq_hi);
    else if (bx < 704) prep_x(mem0,  384, 1024, bx - 512,  32, Xm0_hi);
    else if (bx < 800) prep_x(mem1,  768,  256, bx - 704,   8, Xm1_hi);
    else {
        int r = bx - 800;
        if (r < 16)       prep_w(Wq,    256, r,       Whi + OFF_WQ);
        else if (r < 40)  prep_w(Wk0,   384, r - 16,  Whi + OFF_WK0);
        else if (r < 64)  prep_w(Wv0,   384, r - 40,  Whi + OFF_WV0);
        else if (r < 112) prep_w(Wk1,   768, r - 64,  Whi + OFF_WK1);
        else if (r < 160) prep_w(Wv1,   768, r - 112, Whi + OFF_WV1);
        else              prep_w(Wfuse, 512, r - 160, Whi + OFF_WFUSE);
    }
}

// ---------------------------------------------------------------------------
// 1-term bf16 MFMA GEMM core (proj): D = Ahi·Bhi (+bias).
// Tile 128 rows x 64 cols, 4 waves = 4 row-quarters (32x64 each, acc 2x4).
// LDS: A 16 KB (128x64) + B 8 KB (64x64) = 24 KB. 2-phase pipelined staging.
// B-plane half-tile addressing: unit = ((bn>>1)*CC + ck)<<10 + (bn&1)*512
// (fusemm R12-proven slab formula). Outputs bit-identical to the 128x128
// tiling — only the independent-output partitioning changed.
// ---------------------------------------------------------------------------
__device__ __forceinline__ void gemm_core(
    const u16* __restrict__ Ahi, const u16* __restrict__ Bhi,
    const float* __restrict__ bias, u16* __restrict__ Y,
    int CC, int am, int bn, u16* smem)
{
    const int t = threadIdx.x, lane = t & 63, w = t >> 6;
    const int l15 = lane & 15, kg = lane >> 4;

    f32x4 acc[2][4];
    #pragma unroll
    for (int a = 0; a < 2; a++)
        #pragma unroll
        for (int b2 = 0; b2 < 4; b2++)
            acc[a][b2] = (f32x4){0.f, 0.f, 0.f, 0.f};

    bf16x8 stgA[4], stgB[2];
    // ---- prologue: load chunk 0 ----
    {
        const size_t aoff = ((size_t)(am * CC)) << 13;                       // u16
        const size_t boff = ((((size_t)(bn >> 1) * CC) << 10) + (size_t)(bn & 1) * 512) * 8;
        #pragma unroll
        for (int it = 0; it < 4; it++)
            stgA[it] = *(const bf16x8*)(Ahi + aoff + (size_t)(t + it * 256) * 8);
        #pragma unroll
        for (int it = 0; it < 2; it++)
            stgB[it] = *(const bf16x8*)(Bhi + boff + (size_t)(t + it * 256) * 8);
    }

    for (int ck = 0; ck < CC; ck++) {
        __syncthreads();   // prior chunk's LDS reads done
        #pragma unroll
        for (int it = 0; it < 4; it++)
            *(bf16x8*)(smem + (size_t)(t + it * 256) * 8) = stgA[it];
        #pragma unroll
        for (int it = 0; it < 2; it++)
            *(bf16x8*)(smem + 8192 + (size_t)(t + it * 256) * 8) = stgB[it];
        __syncthreads();   // chunk staged

        // ---- prefetch next chunk (clamped; last-iter re-read harmless) ----
        {
            const int cn = (ck + 1 < CC) ? ck + 1 : ck;
            const size_t aoff = ((size_t)(am * CC + cn)) << 13;
            const size_t boff = ((((size_t)(bn >> 1) * CC + cn) << 10) + (size_t)(bn & 1) * 512) * 8;
            #pragma unroll
            for (int it = 0; it < 4; it++)
                stgA[it] = *(const bf16x8*)(Ahi + aoff + (size_t)(t + it * 256) * 8);
            #pragma unroll
            for (int it = 0; it < 2; it++)
                stgB[it] = *(const bf16x8*)(Bhi + boff + (size_t)(t + it * 256) * 8);
        }

        // ---- compute: 2 k-steps of 32 ----
        #pragma unroll
        for (int kk = 0; kk < 2; kk++) {
            bf16x8 ah[2], bh[4];
            #pragma unroll
            for (int tr = 0; tr < 2; tr++) {
                int row = w * 32 + tr * 16 + l15;
                int off = row * 64 + (((kk * 4 + kg) ^ (row & 7)) << 3);
                ah[tr] = *(const bf16x8*)(smem + off);
            }
            #pragma unroll
            for (int tc = 0; tc < 4; tc++) {
                int row = tc * 16 + l15;
                int off = row * 64 + (((kk * 4 + kg) ^ (row & 7)) << 3);
                bh[tc] = *(const bf16x8*)(smem + 8192 + off);
            }
            #pragma unroll
            for (int tr = 0; tr < 2; tr++)
                #pragma unroll
                for (int tc = 0; tc < 4; tc++)
                    acc[tr][tc] = __builtin_amdgcn_mfma_f32_16x16x32_bf16(ah[tr], bh[tc], acc[tr][tc], 0, 0, 0);
        }
    }

    // ---- epilogue: D row = kg*4+i, col = l15 (m89-verified) ----
    float bv[4];
    #pragma unroll
    for (int tc = 0; tc < 4; tc++)
        bv[tc] = bias[bn * 64 + tc * 16 + l15];
    #pragma unroll
    for (int tr = 0; tr < 2; tr++) {
        #pragma unroll
        for (int i = 0; i < 4; i++) {
            int rp = am * 128 + w * 32 + tr * 16 + kg * 4 + i;
            u16* yr = Y + (size_t)rp * 256 + bn * 64 + l15;
            #pragma unroll
            for (int tc = 0; tc < 4; tc++)
                yr[tc * 16] = f2bf(acc[tr][tc][i] + bv[tc]);
        }
    }
}

// proj: q / k0 / v0 / k1 / v1 in one 416-block dispatch (1-term bf16)
__global__ __launch_bounds__(256) void projmm_k(
    const u16* __restrict__ Xq_hi, const u16* __restrict__ Xm0_hi,
    const u16* __restrict__ Xm1_hi, const u16* __restrict__ Whi,
    const float* __restrict__ bq, const float* __restrict__ bk0, const float* __restrict__ bv0,
    const float* __restrict__ bk1, const float* __restrict__ bv1,
    u16* qT, u16* k0T, u16* v0T, u16* k1T, u16* v1T)
{
    __shared__ u16 smem[12288];   // 24 KB
    const int bx = blockIdx.x;
    if (bx < 256) {
        gemm_core(Xq_hi, Whi + OFF_WQ, bq, qT, 4, bx >> 2, bx & 3, smem);
    } else if (bx < 320) {
        const int r = bx - 256;
        gemm_core(Xm0_hi, Whi + OFF_WK0, bk0, k0T, 6, r >> 2, r & 3, smem);
    } else if (bx < 384) {
        const int r = bx - 320;
        gemm_core(Xm0_hi, Whi + OFF_WV0, bv0, v0T, 6, r >> 2, r & 3, smem);
    } else if (bx < 400) {
        const int r = bx - 384;
        gemm_core(Xm1_hi, Whi + OFF_WK1, bk1, k1T, 12, r >> 2, r & 3, smem);
    } else {
        const int r = bx - 400;
        gemm_core(Xm1_hi, Whi + OFF_WV1, bv1, v1T, 12, r >> 2, r & 3, smem);
    }
}

// ---------------------------------------------------------------------------
// fuse GEMM (1-term, R12-proven): out[o][p] = Whi_fuse[o]·fused[p] + bfuse.
// ---------------------------------------------------------------------------
__global__ __launch_bounds__(256) void fusemm_k(
    const u16* __restrict__ Whi, const u16* __restrict__ fhi,
    const float* __restrict__ bias, float* __restrict__ out)
{
    __shared__ u16 smem[12288];
    const int t = threadIdx.x, lane = t & 63, w = t >> 6;
    const int wr = w >> 1, wc = w & 1;
    const int l15 = lane & 15;
    const int am = blockIdx.x & 3, bn = blockIdx.x >> 2;
    const u16* A = Whi + OFF_WFUSE;

    f32x4 acc[2][4];
    #pragma unroll
    for (int a = 0; a < 2; a++)
        #pragma unroll
        for (int b2 = 0; b2 < 4; b2++)
            acc[a][b2] = (f32x4){0.f, 0.f, 0.f, 0.f};

    bf16x8 stgA[2], stgB[4];
    {
        const size_t aoff = (((size_t)(am >> 1) * 8) << 10) + (size_t)(am & 1) * 512;
        const size_t boff = ((size_t)(bn * 8)) << 10;
        #pragma unroll
        for (int it = 0; it < 2; it++)
            stgA[it] = *(const bf16x8*)(A + (aoff + t + it * 256) * 8);
        #pragma unroll
        for (int it = 0; it < 4; it++)
            stgB[it] = *(const bf16x8*)(fhi + (boff + t + it * 256) * 8);
    }

    for (int ck = 0; ck < 8; ck++) {
        __syncthreads();
        #pragma unroll
        for (int it = 0; it < 2; it++)
            *(bf16x8*)(smem + (size_t)(t + it * 256) * 8) = stgA[it];
        #pragma unroll
        for (int it = 0; it < 4; it++)
            *(bf16x8*)(smem + 4096 + (size_t)(t + it * 256) * 8) = stgB[it];
        __syncthreads();

        {
            const int cn = (ck + 1 < 8) ? ck + 1 : ck;
            const size_t aoff = (((size_t)(am >> 1) * 8 + cn) << 10) + (size_t)(am & 1) * 512;
            const size_t boff = ((size_t)(bn * 8 + cn)) << 10;
            #pragma unroll
            for (int it = 0; it < 2; it++)
                stgA[it] = *(const bf16x8*)(A + (aoff + t + it * 256) * 8);
            #pragma unroll
            for (int it = 0; it < 4; it++)
                stgB[it] = *(const bf16x8*)(fhi + (boff + t + it * 256) * 8);
        }

        #pragma unroll
        for (int kk = 0; kk < 2; kk++) {
            bf16x8 ah[2], bh[4];
            #pragma unroll
            for (int tr = 0; tr < 2; tr++) {
                int row = wr * 32 + tr * 16 + l15;
                int off = row * 64 + (((kk * 4 + (lane >> 4)) ^ (row & 7)) << 3);
                ah[tr] = *(const bf16x8*)(smem + off);
            }
            #pragma unroll
            for (int tc = 0; tc < 4; tc++) {
                int row = wc * 64 + tc * 16 + l15;
                int off = row * 64 + (((kk * 4 + (lane >> 4)) ^ (row & 7)) << 3);
                bh[tc] = *(const bf16x8*)(smem + 4096 + off);
            }
            #pragma unroll
            for (int tr = 0; tr < 2; tr++)
                #pragma unroll
                for (int tc = 0; tc < 4; tc++)
                    acc[tr][tc] = __builtin_amdgcn_mfma_f32_16x16x32_bf16(ah[tr], bh[tc], acc[tr][tc], 0, 0, 0);
        }
    }

    #pragma unroll
    for (int tr = 0; tr < 2; tr++) {
        #pragma unroll
        for (int i = 0; i < 4; i++) {
            const int o = am * 64 + wr * 32 + tr * 16 + ((lane >> 4) << 2) + i;
            const float bv = bias[o];
            #pragma unroll
            for (int tc = 0; tc < 4; tc++) {
                const int pcol = bn * 128 + wc * 64 + tc * 16 + l15;
                out[(size_t)((pcol >> 12) * 256 + o) * 4096 + (pcol & 4095)] = acc[tr][tc][i] + bv;
            }
        }
    }
}

// ---------------------------------------------------------------------------
// MFMA attention (R13-proven, unchanged). One wave per (b, head, 4x4 q-tile),
// no block barrier. SCALE=0: 8x8 64-cand frame. SCALE=1: 5x6 30-cand frame.
// ---------------------------------------------------------------------------
template<int SCALE>
__device__ __forceinline__ void attn_mfma(
    const u16* __restrict__ qT, const u16* __restrict__ kT,
    const u16* __restrict__ vT, u16* __restrict__ fhi,
    int b, int n, int ty, int tx, int lane, u16* s_lds)
{
    constexpr int HM = SCALE ? 16 : 32;
    constexpr int NT = SCALE ? 2 : 4;      // 16-cand tiles
    const int qy0 = ty * 4, qx0 = tx * 4;
    const int ay0 = SCALE ? (qy0 >> 2) : (qy0 >> 1);
    const int ax0 = SCALE ? (qx0 >> 2) : (qx0 >> 1);
    const int l15 = lane & 15, kg = lane >> 4;

    const int pA = (b * 64 + qy0 + (l15 >> 2)) * 64 + qx0 + (l15 & 3);
    const bf16x8 qf = *(const bf16x8*)(qT + (size_t)pA * 256 + n * 32 + kg * 8);

    f32x4 s[NT];
    #pragma unroll
    for (int t = 0; t < NT; t++) {
        const int cand = t * 16 + l15;
        const int wy = SCALE ? (cand / 6) : (cand >> 3);
        const int wx = SCALE ? (cand % 6) : (cand & 7);
        const int my = SCALE ? (ay0 + (wy - 2) * 2) : (ay0 - 3 + wy);
        const int mx = SCALE ? (ax0 + (wx - 2) * 2) : (ax0 - 3 + wx);
        const int myc = min(max(my, 0), HM - 1), mxc = min(max(mx, 0), HM - 1);
        const bf16x8 kf = *(const bf16x8*)(kT + (size_t)((b * HM + myc) * HM + mxc) * 256 + n * 32 + kg * 8);
        s[t] = __builtin_amdgcn_mfma_f32_16x16x32_bf16(qf, kf, (f32x4){0.f, 0.f, 0.f, 0.f}, 0, 0, 0);
    }

    const float scl = 0.17677669529663687f;
    float sv[NT][4];
    #pragma unroll
    for (int t = 0; t < NT; t++) {
        const int cand = t * 16 + l15;
        const int wy = SCALE ? (cand / 6) : (cand >> 3);
        const int wx = SCALE ? (cand % 6) : (cand & 7);
        const int my = SCALE ? (ay0 + (wy - 2) * 2) : (ay0 - 3 + wy);
        const int mx = SCALE ? (ax0 + (wx - 2) * 2) : (ax0 - 3 + wx);
        const bool inb = (my >= 0) && (my < HM) && (mx >= 0) && (mx < HM);
        #pragma unroll
        for (int i = 0; i < 4; i++) {
            bool ok;
            if (SCALE) {
                ok = inb && (wy < 5) && (wx < 5);
            } else {
                const int r = kg * 4 + i;
                const int dy2 = (r >> 2) >> 1, dx2 = (r & 3) >> 1;
                ok = inb && ((u32)(wy - dy2) <= 6u) && ((u32)(wx - dx2) <= 6u);
            }
            sv[t][i] = ok ? s[t][i] * scl : -1e30f;
        }
    }

    float linv[4];
    #pragma unroll
    for (int i = 0; i < 4; i++) {
        float m = sv[0][i];
        #pragma unroll
        for (int t = 1; t < NT; t++) m = fmaxf(m, sv[t][i]);
        #pragma unroll
        for (int dd = 1; dd < 16; dd <<= 1) m = fmaxf(m, __shfl_xor(m, dd, 64));
        float l = 0.f;
        #pragma unroll
        for (int t = 0; t < NT; t++) { sv[t][i] = __expf(sv[t][i] - m); l += sv[t][i]; }
        #pragma unroll
        for (int dd = 1; dd < 16; dd <<= 1) l += __shfl_xor(l, dd, 64);
        linv[i] = 1.f / l;
    }

    // P -> private LDS slice (no block barrier: intra-wave lgkmcnt ordering)
    #pragma unroll
    for (int t = 0; t < NT; t++)
        #pragma unroll
        for (int i = 0; i < 4; i++)
            s_lds[(kg * 4 + i) * 68 + t * 16 + l15] = f2bf(sv[t][i]);

    f32x4 o[2] = {(f32x4){0.f,0.f,0.f,0.f}, (f32x4){0.f,0.f,0.f,0.f}};
    #pragma unroll
    for (int h = 0; h < NT / 2; h++) {
        const bf16x8 pa = *(const bf16x8*)(s_lds + l15 * 68 + h * 32 + kg * 8);
        #pragma unroll
        for (int c = 0; c < 2; c++) {
            bf16x8 vf;
            #pragma unroll
            for (int j = 0; j < 8; j++) {
                const int cand = h * 32 + kg * 8 + j;
                const int wy = SCALE ? (cand / 6) : (cand >> 3);
                const int wx = SCALE ? (cand % 6) : (cand & 7);
                int my = SCALE ? (ay0 + (wy - 2) * 2) : (ay0 - 3 + wy);
                int mx = SCALE ? (ax0 + (wx - 2) * 2) : (ax0 - 3 + wx);
                my = min(max(my, 0), HM - 1); mx = min(max(mx, 0), HM - 1);
                vf[j] = (short)vT[(size_t)((b * HM + my) * HM + mx) * 256 + n * 32 + c * 16 + l15];
            }
            o[c] = __builtin_amdgcn_mfma_f32_16x16x32_bf16(pa, vf, o[c], 0, 0, 0);
        }
    }

    #pragma unroll
    for (int c = 0; c < 2; c++) {
        #pragma unroll
        for (int i = 0; i < 4; i++) {
            const int r = kg * 4 + i;
            const int p = (b * 64 + qy0 + (r >> 2)) * 64 + qx0 + (r & 3);
            const int ch = (SCALE ? 256 : 0) + n * 32 + c * 16 + l15;
            fhi[sw_unit(p, ch, 8) * 8 + (ch & 7)] = f2bf(o[c][i] * linv[i]);
        }
    }
}

__global__ __launch_bounds__(256) void attn_k(
    const u16* __restrict__ qT,
    const u16* __restrict__ k0T, const u16* __restrict__ v0T,
    const u16* __restrict__ k1T, const u16* __restrict__ v1T,
    u16* __restrict__ fhi)
{
    __shared__ u16 s_lds[4][16 * 68];
    const int t = threadIdx.x, w = t >> 6, lane = t & 63;
    const int bx = blockIdx.x;
    const int sc = bx >> 10;
    const int tile = (bx & 1023) * 4 + w;
    const int b = tile >> 11, n = (tile >> 8) & 7;
    const int ty = (tile >> 4) & 15, tx = tile & 15;
    if (sc == 0) attn_mfma<0>(qT, k0T, v0T, fhi, b, n, ty, tx, lane, s_lds[w]);
    else         attn_mfma<1>(qT, k1T, v1T, fhi, b, n, ty, tx, lane, s_lds[w]);
}

// ---------------------------------------------------------------------------
extern "C" void kernel_launch(void* const* d_in, const int* in_sizes, int n_in,
                              void* d_out, int out_size, void* d_ws, size_t ws_size,
                              hipStream_t stream)
{
    const float* query = (const float*)d_in[0];
    const float* mem0  = (const float*)d_in[1];
    const float* mem1  = (const float*)d_in[2];
    const float* Wq    = (const float*)d_in[3];  const float* bq    = (const float*)d_in[4];
    const float* Wk0   = (const float*)d_in[5];  const float* bk0   = (const float*)d_in[6];
    const float* Wv0   = (const float*)d_in[7];  const float* bv0   = (const float*)d_in[8];
    const float* Wk1   = (const float*)d_in[9];  const float* bk1   = (const float*)d_in[10];
    const float* Wv1   = (const float*)d_in[11]; const float* bv1   = (const float*)d_in[12];
    const float* Wfuse = (const float*)d_in[13]; const float* bfuse = (const float*)d_in[14];
    float* out = (float*)d_out;

    char* ws = (char*)d_ws;
    u16* qT       = (u16*)(ws + 0);            // 4 MB (bf16 pixel-major)
    u16* k0T      = (u16*)(ws + 8388608);      // 1 MB
    u16* v0T      = (u16*)(ws + 10485760);     // 1 MB
    u16* k1T      = (u16*)(ws + 12582912);     // 256 KB
    u16* v1T      = (u16*)(ws + 13107200);     // 256 KB
    u16* Whi      = (u16*)(ws + 13631488);     // 1.5 MB
    u16* Xm0_hi   = (u16*)(ws + 16777216);     // 1.5 MB
    u16* Xm1_hi   = (u16*)(ws + 19922944);     // 768 KB
    u16* Xq_hi    = (u16*)(ws + 21495808);     // 4 MB
    u16* fhi      = Xq_hi;                     // fused plane (8 MB: Xq_hi + next 4 MB)

    prep_k<<<dim3(992), 256, 0, stream>>>(
        query, mem0, mem1, Wq, Wk0, Wv0, Wk1, Wv1, Wfuse,
        Xq_hi, Xm0_hi, Xm1_hi, Whi);

    projmm_k<<<dim3(416), 256, 0, stream>>>(
        Xq_hi, Xm0_hi, Xm1_hi, Whi,
        bq, bk0, bv0, bk1, bv1, qT, k0T, v0T, k1T, v1T);

    attn_k<<<dim3(2048), 256, 0, stream>>>(qT, k0T, v0T, k1T, v1T, fhi);

    fusemm_k<<<dim3(256), 256, 0, stream>>>(Whi, fhi, bfuse, out);
}